// Round 15
// baseline (306.492 us; speedup 1.0000x reference)
//
#include <hip/hip_runtime.h>

// ---------------------------------------------------------------------------
// GAT (3 layers) + attention pooling + regressor.
// GEMMs: split-bf16 MFMA; h stored HEAD-MAJOR [H][N][64].
// Softmax weights precomputed per edge (edge_w*_k) -> aggregate is a pure
// gather-multiply with coalesced weight loads; channel-half split (CH=32)
// makes the per-phase gather working set 2.56MB < 4MB XCD L2.
// N=20000 nodes, E=320000 edges (+N self loops), H=4 heads, C=64, B=16 graphs.
// ---------------------------------------------------------------------------

typedef unsigned short u16;
typedef __attribute__((ext_vector_type(8))) short bf16x8;
typedef __attribute__((ext_vector_type(4))) float f32x4;

__device__ __forceinline__ u16 bf16rn(float x) {
    unsigned u = __float_as_uint(x);
    u += 0x7FFFu + ((u >> 16) & 1u);
    return (u16)(u >> 16);
}
__device__ __forceinline__ float bf16f(u16 h) {
    return __uint_as_float(((unsigned)h) << 16);
}

__device__ __forceinline__ void gload16(const u16* g, u16* l) {
    __builtin_amdgcn_global_load_lds(
        (const __attribute__((address_space(1))) unsigned int*)g,
        (__attribute__((address_space(3))) unsigned int*)l, 16, 0, 0);
}

// ---------------- CSR-by-destination build ----------------
__global__ void edge_hist_k(const int* __restrict__ ei, int E, int n, int* __restrict__ deg) {
    int i = blockIdx.x * blockDim.x + threadIdx.x;
    if (i >= E + n) return;
    int dst = (i < E) ? ei[E + i] : (i - E);   // self-loop for i >= E
    atomicAdd(&deg[dst], 1);
}

// 3-pass hierarchical exclusive scan
__global__ void scan_p1_k(const int* __restrict__ deg, int* __restrict__ bsum, int n) {
    __shared__ int red[256];
    int tid = threadIdx.x;
    int i = blockIdx.x * 256 + tid;
    int v = (i < n) ? deg[i] : 0;
    red[tid] = v;
    __syncthreads();
    for (int off = 128; off; off >>= 1) {
        if (tid < off) red[tid] += red[tid + off];
        __syncthreads();
    }
    if (tid == 0) bsum[blockIdx.x] = red[0];
}

__global__ __launch_bounds__(1024) void scan_p2_k(int* __restrict__ bsum, int nb) {
    __shared__ int part[1024];
    int tid = threadIdx.x;
    int v = (tid < nb) ? bsum[tid] : 0;
    part[tid] = v;
    __syncthreads();
    for (int off = 1; off < 1024; off <<= 1) {
        int t = (tid >= off) ? part[tid - off] : 0;
        __syncthreads();
        part[tid] += t;
        __syncthreads();
    }
    if (tid < nb) bsum[tid] = part[tid] - v;      // exclusive
}

__global__ void scan_p3_k(const int* __restrict__ deg, const int* __restrict__ bsum,
                          int* __restrict__ rowptr, int* __restrict__ cursor, int n) {
    __shared__ int part[256];
    int tid = threadIdx.x;
    int i = blockIdx.x * 256 + tid;
    int v = (i < n) ? deg[i] : 0;
    part[tid] = v;
    __syncthreads();
    for (int off = 1; off < 256; off <<= 1) {
        int t = (tid >= off) ? part[tid - off] : 0;
        __syncthreads();
        part[tid] += t;
        __syncthreads();
    }
    int excl = part[tid] - v + bsum[blockIdx.x];
    if (i < n) { rowptr[i] = excl; cursor[i] = excl; }
    if (i == n - 1) rowptr[n] = excl + v;
}

__global__ void edge_scatter_k(const int* __restrict__ ei, int E, int n,
                               int* __restrict__ cursor, int* __restrict__ srcs) {
    int i = blockIdx.x * blockDim.x + threadIdx.x;
    if (i >= E + n) return;
    int src, dst;
    if (i < E) { src = ei[i]; dst = ei[E + i]; }
    else       { src = i - E; dst = src; }
    int pos = atomicAdd(&cursor[dst], 1);
    srcs[pos] = src;
}

// ---------------- bf16 split conversions ----------------
__global__ void split_bf16_k(const float* __restrict__ in, u16* __restrict__ hi,
                             u16* __restrict__ lo, int n4) {
    int i = blockIdx.x * 256 + threadIdx.x;
    if (i >= n4) return;
    float4 v = reinterpret_cast<const float4*>(in)[i];
    u16 hx = bf16rn(v.x), hy = bf16rn(v.y), hz = bf16rn(v.z), hw = bf16rn(v.w);
    ushort4 H = make_ushort4(hx, hy, hz, hw);
    ushort4 L = make_ushort4(bf16rn(v.x - bf16f(hx)), bf16rn(v.y - bf16f(hy)),
                             bf16rn(v.z - bf16f(hz)), bf16rn(v.w - bf16f(hw)));
    reinterpret_cast<ushort4*>(hi)[i] = H;
    reinterpret_cast<ushort4*>(lo)[i] = L;
}

// W[K][Nn] row-major -> transposed split Wt[Nn][K] (hi, lo)
__global__ void splitT_bf16_k(const float* __restrict__ W, u16* __restrict__ thi,
                              u16* __restrict__ tlo, int K, int Nn) {
    int idx = blockIdx.x * 256 + threadIdx.x;
    if (idx >= K * Nn) return;
    int k = idx / Nn, nn = idx - k * Nn;
    float v = W[idx];
    u16 h = bf16rn(v);
    u16 l = bf16rn(v - bf16f(h));
    thi[(size_t)nn * K + k] = h;
    tlo[(size_t)nn * K + k] = l;
}

// ---------------- split-bf16 MFMA GEMM, LDS-staged A, fused attn scores ----
template <int NF>
__global__ __launch_bounds__(256) void gemm_lds_k(
        const u16* __restrict__ Ahi, const u16* __restrict__ Alo,
        const u16* __restrict__ Bthi, const u16* __restrict__ Btlo,
        float* __restrict__ C,
        const float* __restrict__ a_src, const float* __restrict__ a_dst,
        float* __restrict__ esrc, float* __restrict__ edst,
        int M, int Nn, int K) {
    __shared__ u16 Ah[2][4][64 * 8];   // [buf][kg][row*8]
    __shared__ u16 Al[2][4][64 * 8];
    const int mb = (M + 63) >> 6;
    const int mi = blockIdx.x % mb;
    const int ni = blockIdx.x / mb;
    const int m0 = mi * 64;
    const int n0 = ni * (NF * 64);
    const int tid = threadIdx.x;
    const int wv = tid >> 6;
    const int lane = tid & 63;
    const int rr = lane & 15;
    const int kg = lane >> 4;

    int srow = m0 + lane; if (srow > M - 1) srow = M - 1;
    const u16* sh = Ahi + (size_t)srow * K + wv * 8;
    const u16* sl = Alo + (size_t)srow * K + wv * 8;

    const u16* pbh[NF];
    const u16* pbl[NF];
#pragma unroll
    for (int nf = 0; nf < NF; ++nf) {
        int col = n0 + (wv * NF + nf) * 16 + rr;
        pbh[nf] = Bthi + (size_t)col * K + kg * 8;
        pbl[nf] = Btlo + (size_t)col * K + kg * 8;
    }

    f32x4 acc[4][NF];
#pragma unroll
    for (int mf = 0; mf < 4; ++mf)
#pragma unroll
        for (int nf = 0; nf < NF; ++nf) acc[mf][nf] = (f32x4){0.f, 0.f, 0.f, 0.f};

    bf16x8 bhc[NF], blc[NF], bhn[NF], bln[NF];
#pragma unroll
    for (int nf = 0; nf < NF; ++nf) {
        bhc[nf] = *reinterpret_cast<const bf16x8*>(pbh[nf]);
        blc[nf] = *reinterpret_cast<const bf16x8*>(pbl[nf]);
    }
    gload16(sh, &Ah[0][wv][0]);
    gload16(sl, &Al[0][wv][0]);
    __syncthreads();

    const int NT = K >> 5;
    for (int t = 0; t < NT; ++t) {
        const int cur = t & 1;
        if (t + 1 < NT) {
            const int kc = (t + 1) << 5;
#pragma unroll
            for (int nf = 0; nf < NF; ++nf) {
                bhn[nf] = *reinterpret_cast<const bf16x8*>(pbh[nf] + kc);
                bln[nf] = *reinterpret_cast<const bf16x8*>(pbl[nf] + kc);
            }
            gload16(sh + kc, &Ah[cur ^ 1][wv][0]);
            gload16(sl + kc, &Al[cur ^ 1][wv][0]);
        }
        bf16x8 ah[4], al[4];
#pragma unroll
        for (int mf = 0; mf < 4; ++mf) {
            ah[mf] = *reinterpret_cast<const bf16x8*>(&Ah[cur][kg][(mf * 16 + rr) * 8]);
            al[mf] = *reinterpret_cast<const bf16x8*>(&Al[cur][kg][(mf * 16 + rr) * 8]);
        }
#pragma unroll
        for (int mf = 0; mf < 4; ++mf)
#pragma unroll
            for (int nf = 0; nf < NF; ++nf) {
                acc[mf][nf] = __builtin_amdgcn_mfma_f32_16x16x32_bf16(ah[mf], bhc[nf], acc[mf][nf], 0, 0, 0);
                acc[mf][nf] = __builtin_amdgcn_mfma_f32_16x16x32_bf16(ah[mf], blc[nf], acc[mf][nf], 0, 0, 0);
                acc[mf][nf] = __builtin_amdgcn_mfma_f32_16x16x32_bf16(al[mf], bhc[nf], acc[mf][nf], 0, 0, 0);
            }
#pragma unroll
        for (int nf = 0; nf < NF; ++nf) { bhc[nf] = bhn[nf]; blc[nf] = bln[nf]; }
        __syncthreads();
    }

    // ---- C store (head-major) ----
#pragma unroll
    for (int mf = 0; mf < 4; ++mf)
#pragma unroll
        for (int nf = 0; nf < NF; ++nf) {
            int col = n0 + (wv * NF + nf) * 16 + rr;
            float* cb = C + ((size_t)(col >> 6) * M) * 64 + (col & 63);
#pragma unroll
            for (int rg = 0; rg < 4; ++rg) {
                int row = m0 + mf * 16 + kg * 4 + rg;
                if (row < M) cb[(size_t)row * 64] = acc[mf][nf][rg];
            }
        }

    // ---- fused attention scores: per-row dot with a_src / a_dst ----
    float asv[NF], adv[NF];
#pragma unroll
    for (int nf = 0; nf < NF; ++nf) {
        int col = n0 + (wv * NF + nf) * 16 + rr;
        asv[nf] = a_src[col];
        adv[nf] = a_dst[col];
    }
    float ps[4][4], pd[4][4];   // [mf][rg]
#pragma unroll
    for (int mf = 0; mf < 4; ++mf)
#pragma unroll
        for (int rg = 0; rg < 4; ++rg) {
            float s = 0.f, dvv = 0.f;
#pragma unroll
            for (int nf = 0; nf < NF; ++nf) {
                s = fmaf(acc[mf][nf][rg], asv[nf], s);
                dvv = fmaf(acc[mf][nf][rg], adv[nf], dvv);
            }
#pragma unroll
            for (int off = 1; off < 16; off <<= 1) {
                s += __shfl_xor(s, off);
                dvv += __shfl_xor(dvv, off);
            }
            ps[mf][rg] = s;
            pd[mf][rg] = dvv;
        }
    // cross-wave combine via LDS (reuse Ah; all reads of it completed)
    float* sm_src = (float*)&Ah[0][0][0];     // [4 waves][64 rows]
    float* sm_dst = sm_src + 256;
    if (rr == 0) {
#pragma unroll
        for (int mf = 0; mf < 4; ++mf)
#pragma unroll
            for (int rg = 0; rg < 4; ++rg) {
                int rl = mf * 16 + kg * 4 + rg;
                sm_src[wv * 64 + rl] = ps[mf][rg];
                sm_dst[wv * 64 + rl] = pd[mf][rg];
            }
    }
    __syncthreads();
    if (tid < 64) {
        int row = m0 + tid;
        if (row < M) {
            const int HTOT = Nn >> 6;
            constexpr int WPH = 4 / NF;        // waves per head
#pragma unroll
            for (int hl = 0; hl < NF; ++hl) {
                float es = 0.f, edv = 0.f;
#pragma unroll
                for (int w = 0; w < WPH; ++w) {
                    es += sm_src[(hl * WPH + w) * 64 + tid];
                    edv += sm_dst[(hl * WPH + w) * 64 + tid];
                }
                int hg = ni * NF + hl;
                esrc[(size_t)row * HTOT + hg] = es;
                edst[(size_t)row * HTOT + hg] = edv;
            }
        }
    }
}

// ---------------- per-edge softmax weights (4 heads) -----------------------
// Wave per dst; lane = (hh=lane>>4, jj=lane&15). wbuf layout [h][edge].
__global__ __launch_bounds__(256) void edge_w4_k(
        const float* __restrict__ esrc, const float* __restrict__ edst,
        const int* __restrict__ rowptr, const int* __restrict__ srcs,
        float* __restrict__ wbuf, float* __restrict__ den, int n, int Etot) {
    int wv = threadIdx.x >> 6;
    int d = blockIdx.x * 4 + wv;
    int lane = threadIdx.x & 63;
    if (d >= n) return;
    int hh = lane >> 4, jj = lane & 15;
    float ed = edst[d * 4 + hh];
    int lo = rowptr[d], hi = rowptr[d + 1];
    float dacc = 0.f;
    for (int base = lo; base < hi; base += 16) {
        int idx = base + jj;
        bool val = idx < hi;
        int s = srcs[val ? idx : lo];
        float e = esrc[s * 4 + hh] + ed;
        e = (e >= 0.f) ? e : 0.2f * e;          // leaky_relu(0.2)
        float w = val ? __expf(e) : 0.f;
        if (val) wbuf[(size_t)hh * Etot + idx] = w;
        dacc += w;
    }
#pragma unroll
    for (int off = 1; off < 16; off <<= 1) dacc += __shfl_xor(dacc, off);
    if (jj == 0) den[d * 4 + hh] = dacc;
}

// ---------------- per-edge softmax weights (1 head) ------------------------
__global__ __launch_bounds__(256) void edge_w1_k(
        const float* __restrict__ esrc, const float* __restrict__ edst,
        const int* __restrict__ rowptr, const int* __restrict__ srcs,
        float* __restrict__ wbuf, float* __restrict__ den, int n) {
    int wv = threadIdx.x >> 6;
    int d = blockIdx.x * 4 + wv;
    int lane = threadIdx.x & 63;
    if (d >= n) return;
    float ed = edst[d];
    int lo = rowptr[d], hi = rowptr[d + 1];
    float dacc = 0.f;
    for (int base = lo; base < hi; base += 64) {
        int idx = base + lane;
        bool val = idx < hi;
        int s = srcs[val ? idx : lo];
        float e = esrc[s] + ed;
        e = (e >= 0.f) ? e : 0.2f * e;
        float w = val ? __expf(e) : 0.f;
        if (val) wbuf[idx] = w;
        dacc += w;
    }
#pragma unroll
    for (int off = 1; off < 64; off <<= 1) dacc += __shfl_xor(dacc, off);
    if (lane == 0) den[d] = dacc;
}

// ---------------- GAT aggregation: pure gather-multiply, CH=32 -------------
// hm head-major [4][n][64]; blockIdx.y = head*2 + channel-half (8 phases,
// per-phase working set 2.56MB < 4MB L2). Wave per (dst,head,half);
// lane = (es=lane>>3 edge slot, cq=lane&7 channel quad). Per 64-edge chunk:
// coalesced {src,w} load -> LDS publish -> 8 slots x 8 edges in flight.
#define HM_STEP(K, T, R)                                                       \
    if (cnt > 8 * K) {                                                         \
        float wk = __int_as_float(T.y);                                        \
        acc.x = fmaf(wk, R.x, acc.x); acc.y = fmaf(wk, R.y, acc.y);            \
        acc.z = fmaf(wk, R.z, acc.z); acc.w = fmaf(wk, R.w, acc.w);            \
    }

__global__ __launch_bounds__(256) void gat_aggregate_hm_k(
        const float* __restrict__ hm, const float* __restrict__ wbuf,
        const float* __restrict__ den4, const int* __restrict__ rowptr,
        const int* __restrict__ srcs, const float* __restrict__ bias,
        u16* __restrict__ ghi, u16* __restrict__ glo, int n, int Etot) {
    __shared__ int2 swb[4][64];
    int wv = threadIdx.x >> 6;
    int d = blockIdx.x * 4 + wv;
    int lane = threadIdx.x & 63;
    int hh = blockIdx.y >> 1;                   // head
    int ch = blockIdx.y & 1;                    // channel half
    if (d >= n) return;
    const float* hbase = hm + (size_t)hh * n * 64 + ch * 32;
    const int es = lane >> 3;                   // edge slot 0..7
    const int cq = lane & 7;                    // channel quad in half
    int2* swv = swb[wv];
    int lo = rowptr[d], hi = rowptr[d + 1];
    float4 acc = make_float4(0.f, 0.f, 0.f, 0.f);
    for (int base = lo; base < hi; base += 64) {
        int cnt = min(64, hi - base);
        int idx = base + lane;
        bool val = lane < cnt;
        int s = srcs[val ? idx : lo];
        float w = val ? wbuf[(size_t)hh * Etot + idx] : 0.f;
        swv[lane] = make_int2(s, __float_as_int(w));
        auto ROW = [&](int2 t) -> float4 {
            return *reinterpret_cast<const float4*>(&hbase[(size_t)t.x * 64 + cq * 4]);
        };
        float4 z = make_float4(0.f, 0.f, 0.f, 0.f);
        int2 zi = make_int2(0, 0);
        int2 t0 = zi, t1 = zi, t2 = zi, t3 = zi, t4 = zi, t5 = zi, t6 = zi, t7 = zi;
        float4 r0 = z, r1 = z, r2 = z, r3 = z, r4 = z, r5 = z, r6 = z, r7 = z;
        t0 = swv[es];           r0 = ROW(t0);
        if (cnt >  8) { t1 = swv[ 8 + es]; r1 = ROW(t1); }
        if (cnt > 16) { t2 = swv[16 + es]; r2 = ROW(t2); }
        if (cnt > 24) { t3 = swv[24 + es]; r3 = ROW(t3); }
        if (cnt > 32) { t4 = swv[32 + es]; r4 = ROW(t4); }
        if (cnt > 40) { t5 = swv[40 + es]; r5 = ROW(t5); }
        if (cnt > 48) { t6 = swv[48 + es]; r6 = ROW(t6); }
        if (cnt > 56) { t7 = swv[56 + es]; r7 = ROW(t7); }
        HM_STEP(0, t0, r0) HM_STEP(1, t1, r1) HM_STEP(2, t2, r2) HM_STEP(3, t3, r3)
        HM_STEP(4, t4, r4) HM_STEP(5, t5, r5) HM_STEP(6, t6, r6) HM_STEP(7, t7, r7)
    }
    // combine the 8 edge slots (lanes differing in bits 3,4,5)
    acc.x += __shfl_xor(acc.x, 8); acc.x += __shfl_xor(acc.x, 16); acc.x += __shfl_xor(acc.x, 32);
    acc.y += __shfl_xor(acc.y, 8); acc.y += __shfl_xor(acc.y, 16); acc.y += __shfl_xor(acc.y, 32);
    acc.z += __shfl_xor(acc.z, 8); acc.z += __shfl_xor(acc.z, 16); acc.z += __shfl_xor(acc.z, 32);
    acc.w += __shfl_xor(acc.w, 8); acc.w += __shfl_xor(acc.w, 16); acc.w += __shfl_xor(acc.w, 32);
    if (es == 0) {
        int c0 = hh * 64 + ch * 32 + cq * 4;
        float inv = 1.f / den4[d * 4 + hh];
        float4 bv = *reinterpret_cast<const float4*>(&bias[c0]);
        float4 o;
        o.x = acc.x * inv + bv.x;
        o.y = acc.y * inv + bv.y;
        o.z = acc.z * inv + bv.z;
        o.w = acc.w * inv + bv.w;
        o.x = (o.x > 0.f) ? o.x : expm1f(o.x);   // ELU
        o.y = (o.y > 0.f) ? o.y : expm1f(o.y);
        o.z = (o.z > 0.f) ? o.z : expm1f(o.z);
        o.w = (o.w > 0.f) ? o.w : expm1f(o.w);
        u16 hx = bf16rn(o.x), hy = bf16rn(o.y), hz = bf16rn(o.z), hw = bf16rn(o.w);
        ushort4 H = make_ushort4(hx, hy, hz, hw);
        ushort4 L = make_ushort4(bf16rn(o.x - bf16f(hx)), bf16rn(o.y - bf16f(hy)),
                                 bf16rn(o.z - bf16f(hz)), bf16rn(o.w - bf16f(hw)));
        *reinterpret_cast<ushort4*>(&ghi[(size_t)d * 256 + c0]) = H;
        *reinterpret_cast<ushort4*>(&glo[(size_t)d * 256 + c0]) = L;
    }
}

// ---------------- layer-3 aggregate (1 head) fused with node attn gate ------
// Pure gather-multiply (weights precomputed); lane = (es=lane>>4, cq=lane&15).
#define A1_STEP(K, T, R)                                                       \
    if (cnt > 4 * K) {                                                         \
        float wk = __int_as_float(T.y);                                        \
        acc.x = fmaf(wk, R.x, acc.x); acc.y = fmaf(wk, R.y, acc.y);            \
        acc.z = fmaf(wk, R.z, acc.z); acc.w = fmaf(wk, R.w, acc.w);            \
    }

__global__ __launch_bounds__(256) void gat_aggregate1_attn_k(
        const float* __restrict__ hin, const float* __restrict__ wbuf,
        const float* __restrict__ den1, const int* __restrict__ rowptr,
        const int* __restrict__ srcs, const float* __restrict__ bias,
        const float* __restrict__ wp, const float* __restrict__ bp,
        float* __restrict__ gout, float* __restrict__ attn, int n) {
    __shared__ int2 swb[4][64];
    int wv = threadIdx.x >> 6;
    int d = blockIdx.x * 4 + wv;
    int lane = threadIdx.x & 63;
    if (d >= n) return;
    const int es = lane >> 4;
    const int cq = lane & 15;
    int2* swv = swb[wv];
    int lo = rowptr[d], hi = rowptr[d + 1];
    float4 acc = make_float4(0.f, 0.f, 0.f, 0.f);
    for (int base = lo; base < hi; base += 64) {
        int cnt = min(64, hi - base);
        int idx = base + lane;
        bool val = lane < cnt;
        int s = srcs[val ? idx : lo];
        float w = val ? wbuf[idx] : 0.f;
        swv[lane] = make_int2(s, __float_as_int(w));
        auto ROW = [&](int2 t) -> float4 {
            return *reinterpret_cast<const float4*>(&hin[(size_t)t.x * 64 + cq * 4]);
        };
        float4 z = make_float4(0.f, 0.f, 0.f, 0.f);
        int2 zi = make_int2(0, 0);
        int2 t0 = zi, t1 = zi, t2 = zi, t3 = zi, t4 = zi, t5 = zi, t6 = zi, t7 = zi;
        float4 r0 = z, r1 = z, r2 = z, r3 = z, r4 = z, r5 = z, r6 = z, r7 = z;
        t0 = swv[es];           r0 = ROW(t0);
        if (cnt >  4) { t1 = swv[ 4 + es]; r1 = ROW(t1); }
        if (cnt >  8) { t2 = swv[ 8 + es]; r2 = ROW(t2); }
        if (cnt > 12) { t3 = swv[12 + es]; r3 = ROW(t3); }
        if (cnt > 16) { t4 = swv[16 + es]; r4 = ROW(t4); }
        if (cnt > 20) { t5 = swv[20 + es]; r5 = ROW(t5); }
        if (cnt > 24) { t6 = swv[24 + es]; r6 = ROW(t6); }
        if (cnt > 28) { t7 = swv[28 + es]; r7 = ROW(t7); }
        A1_STEP(0, t0, r0) A1_STEP(1, t1, r1) A1_STEP(2, t2, r2) A1_STEP(3, t3, r3)
        A1_STEP(4, t4, r4) A1_STEP(5, t5, r5) A1_STEP(6, t6, r6) A1_STEP(7, t7, r7)
        if (cnt > 32) {
            t0 = swv[32 + es];             r0 = ROW(t0);
            if (cnt > 36) { t1 = swv[36 + es]; r1 = ROW(t1); }
            if (cnt > 40) { t2 = swv[40 + es]; r2 = ROW(t2); }
            if (cnt > 44) { t3 = swv[44 + es]; r3 = ROW(t3); }
            if (cnt > 48) { t4 = swv[48 + es]; r4 = ROW(t4); }
            if (cnt > 52) { t5 = swv[52 + es]; r5 = ROW(t5); }
            if (cnt > 56) { t6 = swv[56 + es]; r6 = ROW(t6); }
            if (cnt > 60) { t7 = swv[60 + es]; r7 = ROW(t7); }
            A1_STEP(8, t0, r0)  A1_STEP(9, t1, r1)  A1_STEP(10, t2, r2) A1_STEP(11, t3, r3)
            A1_STEP(12, t4, r4) A1_STEP(13, t5, r5) A1_STEP(14, t6, r6) A1_STEP(15, t7, r7)
        }
    }
    acc.x += __shfl_xor(acc.x, 16); acc.x += __shfl_xor(acc.x, 32);
    acc.y += __shfl_xor(acc.y, 16); acc.y += __shfl_xor(acc.y, 32);
    acc.z += __shfl_xor(acc.z, 16); acc.z += __shfl_xor(acc.z, 32);
    acc.w += __shfl_xor(acc.w, 16); acc.w += __shfl_xor(acc.w, 32);
    int c0 = cq * 4;
    float inv = 1.f / den1[d];
    float4 bv = *reinterpret_cast<const float4*>(&bias[c0]);
    float4 o;
    o.x = acc.x * inv + bv.x;
    o.y = acc.y * inv + bv.y;
    o.z = acc.z * inv + bv.z;
    o.w = acc.w * inv + bv.w;
    o.x = (o.x > 0.f) ? o.x : expm1f(o.x);       // ELU
    o.y = (o.y > 0.f) ? o.y : expm1f(o.y);
    o.z = (o.z > 0.f) ? o.z : expm1f(o.z);
    o.w = (o.w > 0.f) ? o.w : expm1f(o.w);
    if (es == 0)
        *reinterpret_cast<float4*>(&gout[(size_t)d * 64 + c0]) = o;
    // node attention gate: full 64-ch dot (cq lanes each hold 4 channels)
    float4 wv4 = *reinterpret_cast<const float4*>(&wp[c0]);
    float v = o.x * wv4.x + o.y * wv4.y + o.z * wv4.z + o.w * wv4.w;
#pragma unroll
    for (int off = 1; off < 16; off <<= 1) v += __shfl_xor(v, off);
    if (lane == 0) attn[d] = 1.f / (1.f + __expf(-(v + bp[0])));
}

// ---------------- parallel segmented pooling (batch is sorted) --------------
__global__ void pool_partial_k(const float* __restrict__ g3, const float* __restrict__ attn,
                               const int* __restrict__ batch, int n, float* __restrict__ sums) {
    int wid = blockIdx.x * (blockDim.x >> 6) + (threadIdx.x >> 6);
    int lane = threadIdx.x & 63;
    int nwaves = gridDim.x * (blockDim.x >> 6);
    int per = (n + nwaves - 1) / nwaves;
    int i0 = wid * per;
    int i1 = i0 + per;
    if (i1 > n) i1 = n;
    if (i0 >= i1) return;
    int cur = batch[i0];
    float acc = 0.f;
    for (int i = i0; i < i1; ++i) {
        int b = batch[i];
        if (b != cur) {
            atomicAdd(&sums[cur * 64 + lane], acc);
            acc = 0.f;
            cur = b;
        }
        acc += g3[(size_t)i * 64 + lane] * attn[i];
    }
    atomicAdd(&sums[cur * 64 + lane], acc);
}

// ---------------- final regressor: one block, wave per graph ----------------
__global__ void regress_k(const float* __restrict__ sums, const int* __restrict__ batch, int n,
                          const float* __restrict__ wr, const float* __restrict__ br,
                          float* __restrict__ out, int B) {
    int b = threadIdx.x >> 6;
    int lane = threadIdx.x & 63;
    if (b >= B) return;
    int lo = 0, hi = n;
    while (lo < hi) { int mid = (lo + hi) >> 1; if (batch[mid] < b) lo = mid + 1; else hi = mid; }
    int seg_lo = lo;
    lo = 0; hi = n;
    while (lo < hi) { int mid = (lo + hi) >> 1; if (batch[mid] < b + 1) lo = mid + 1; else hi = mid; }
    float cnt = (float)(lo - seg_lo);
    if (cnt < 1.f) cnt = 1.f;
    float v = (sums[b * 64 + lane] / cnt) * wr[lane];
#pragma unroll
    for (int off = 32; off; off >>= 1) v += __shfl_xor(v, off);
    if (lane == 0) out[b] = v + br[0];
}

// ---------------------------------------------------------------------------
extern "C" void kernel_launch(void* const* d_in, const int* in_sizes, int n_in,
                              void* d_out, int out_size, void* d_ws, size_t ws_size,
                              hipStream_t stream) {
    const float* x   = (const float*)d_in[0];
    const int*   ei  = (const int*)d_in[1];
    const int*   bat = (const int*)d_in[2];
    const float* W1  = (const float*)d_in[3];
    const float* as1 = (const float*)d_in[4];
    const float* ad1 = (const float*)d_in[5];
    const float* b1  = (const float*)d_in[6];
    const float* W2  = (const float*)d_in[7];
    const float* as2 = (const float*)d_in[8];
    const float* ad2 = (const float*)d_in[9];
    const float* b2  = (const float*)d_in[10];
    const float* W3  = (const float*)d_in[11];
    const float* as3 = (const float*)d_in[12];
    const float* ad3 = (const float*)d_in[13];
    const float* b3  = (const float*)d_in[14];
    const float* wp  = (const float*)d_in[15];
    const float* bp  = (const float*)d_in[16];
    const float* wr  = (const float*)d_in[17];
    const float* br  = (const float*)d_in[18];
    float* out = (float*)d_out;

    const int N    = in_sizes[2];          // 20000
    const int E    = in_sizes[1] / 2;      // 320000
    const int DIN  = in_sizes[0] / N;      // 128
    const int Etot = E + N;
    const int Bc   = out_size;             // 16

    char* ws = (char*)d_ws;
    size_t off = 0;
    auto alloc = [&](size_t bytes) {
        void* p = ws + off;
        off = (off + bytes + 255) & ~(size_t)255;
        return p;
    };
    int*   deg    = (int*)alloc((size_t)N * 4);
    int*   rowptr = (int*)alloc((size_t)(N + 1) * 4);
    int*   cursor = (int*)alloc((size_t)N * 4);
    int*   bsum   = (int*)alloc((size_t)1024 * 4);
    int*   srcs   = (int*)alloc((size_t)Etot * 4);
    float* bufA   = (float*)alloc((size_t)N * 256 * 4);     // GEMM out h (head-major)
    u16*   Ahi    = (u16*)alloc((size_t)N * 256 * 2);       // x/g split hi
    u16*   Alo    = (u16*)alloc((size_t)N * 256 * 2);       // x/g split lo
    float* h3     = (float*)alloc((size_t)N * 64 * 4);
    float* g3     = (float*)alloc((size_t)N * 64 * 4);
    float* esrc   = (float*)alloc((size_t)N * 4 * 4);
    float* edst   = (float*)alloc((size_t)N * 4 * 4);
    float* wbuf   = (float*)alloc((size_t)Etot * 4 * 4);    // per-edge weights [h][edge]
    float* den4   = (float*)alloc((size_t)N * 4 * 4);
    float* attn   = (float*)alloc((size_t)N * 4);
    float* sums   = (float*)alloc((size_t)Bc * 64 * 4);
    u16*   w1hi   = (u16*)alloc((size_t)256 * DIN * 2);
    u16*   w1lo   = (u16*)alloc((size_t)256 * DIN * 2);
    u16*   w2hi   = (u16*)alloc((size_t)256 * 256 * 2);
    u16*   w2lo   = (u16*)alloc((size_t)256 * 256 * 2);
    u16*   w3hi   = (u16*)alloc((size_t)64 * 256 * 2);
    u16*   w3lo   = (u16*)alloc((size_t)64 * 256 * 2);
    (void)ws_size;

    // CSR build (shared by all layers); hierarchical parallel scan
    hipMemsetAsync(deg, 0, (size_t)N * 4, stream);
    int eb = (Etot + 255) / 256;
    int nb = (N + 255) / 256;              // 79 blocks <= 1024
    edge_hist_k<<<eb, 256, 0, stream>>>(ei, E, N, deg);
    scan_p1_k<<<nb, 256, 0, stream>>>(deg, bsum, N);
    scan_p2_k<<<1, 1024, 0, stream>>>(bsum, nb);
    scan_p3_k<<<nb, 256, 0, stream>>>(deg, bsum, rowptr, cursor, N);
    edge_scatter_k<<<eb, 256, 0, stream>>>(ei, E, N, cursor, srcs);

    // weight splits (transposed) + x split
    splitT_bf16_k<<<(DIN * 256 + 255) / 256, 256, 0, stream>>>(W1, w1hi, w1lo, DIN, 256);
    splitT_bf16_k<<<(256 * 256 + 255) / 256, 256, 0, stream>>>(W2, w2hi, w2lo, 256, 256);
    splitT_bf16_k<<<(256 * 64 + 255) / 256, 256, 0, stream>>>(W3, w3hi, w3lo, 256, 64);
    split_bf16_k<<<(N * DIN / 4 + 255) / 256, 256, 0, stream>>>(x, Ahi, Alo, N * DIN / 4);

    const int mb = (N + 63) / 64;          // 313
    int nb4 = (N + 3) / 4;
    dim3 agg_grid(nb4, 8);                 // head x channel-half phases

    // Layer 1: DIN -> (4,64) concat      (BN=128 -> 2 n-tiles)
    gemm_lds_k<2><<<mb * 2, 256, 0, stream>>>(Ahi, Alo, w1hi, w1lo, bufA, as1, ad1, esrc, edst, N, 256, DIN);
    edge_w4_k<<<nb4, 256, 0, stream>>>(esrc, edst, rowptr, srcs, wbuf, den4, N, Etot);
    gat_aggregate_hm_k<<<agg_grid, 256, 0, stream>>>(bufA, wbuf, den4, rowptr, srcs, b1, Ahi, Alo, N, Etot);

    // Layer 2: 256 -> (4,64) concat
    gemm_lds_k<2><<<mb * 2, 256, 0, stream>>>(Ahi, Alo, w2hi, w2lo, bufA, as2, ad2, esrc, edst, N, 256, 256);
    edge_w4_k<<<nb4, 256, 0, stream>>>(esrc, edst, rowptr, srcs, wbuf, den4, N, Etot);
    gat_aggregate_hm_k<<<agg_grid, 256, 0, stream>>>(bufA, wbuf, den4, rowptr, srcs, b2, Ahi, Alo, N, Etot);

    // Layer 3: 256 -> (1,64) mean + fused node-attention gate   (BN=64)
    gemm_lds_k<1><<<mb, 256, 0, stream>>>(Ahi, Alo, w3hi, w3lo, h3, as3, ad3, esrc, edst, N, 64, 256);
    edge_w1_k<<<nb4, 256, 0, stream>>>(esrc, edst, rowptr, srcs, wbuf, den4, N);
    gat_aggregate1_attn_k<<<nb4, 256, 0, stream>>>(h3, wbuf, den4, rowptr, srcs, b3, wp, bp, g3, attn, N);

    // Attention pool + regressor (parallel)
    hipMemsetAsync(sums, 0, (size_t)Bc * 64 * 4, stream);
    pool_partial_k<<<256, 256, 0, stream>>>(g3, attn, bat, N, sums);
    regress_k<<<1, 1024, 0, stream>>>(sums, bat, N, wr, br, out, Bc);
}

// Round 16
// 269.478 us; speedup vs baseline: 1.1374x; 1.1374x over previous
//
#include <hip/hip_runtime.h>

// ---------------------------------------------------------------------------
// GAT (3 layers) + attention pooling + regressor.
// GEMMs: split-bf16 MFMA; h stored HEAD-MAJOR [H][N][64].
// Aggregates: 2 destinations per wave — both srcs loads, then both row-gather
// batches, then both weight phases (overlapped serial chains).
// N=20000 nodes, E=320000 edges (+N self loops), H=4 heads, C=64, B=16 graphs.
// ---------------------------------------------------------------------------

typedef unsigned short u16;
typedef __attribute__((ext_vector_type(8))) short bf16x8;
typedef __attribute__((ext_vector_type(4))) float f32x4;

__device__ __forceinline__ u16 bf16rn(float x) {
    unsigned u = __float_as_uint(x);
    u += 0x7FFFu + ((u >> 16) & 1u);
    return (u16)(u >> 16);
}
__device__ __forceinline__ float bf16f(u16 h) {
    return __uint_as_float(((unsigned)h) << 16);
}

__device__ __forceinline__ void gload16(const u16* g, u16* l) {
    __builtin_amdgcn_global_load_lds(
        (const __attribute__((address_space(1))) unsigned int*)g,
        (__attribute__((address_space(3))) unsigned int*)l, 16, 0, 0);
}

// ---------------- CSR-by-destination build ----------------
__global__ void edge_hist_k(const int* __restrict__ ei, int E, int n, int* __restrict__ deg) {
    int i = blockIdx.x * blockDim.x + threadIdx.x;
    if (i >= E + n) return;
    int dst = (i < E) ? ei[E + i] : (i - E);   // self-loop for i >= E
    atomicAdd(&deg[dst], 1);
}

// 3-pass hierarchical exclusive scan
__global__ void scan_p1_k(const int* __restrict__ deg, int* __restrict__ bsum, int n) {
    __shared__ int red[256];
    int tid = threadIdx.x;
    int i = blockIdx.x * 256 + tid;
    int v = (i < n) ? deg[i] : 0;
    red[tid] = v;
    __syncthreads();
    for (int off = 128; off; off >>= 1) {
        if (tid < off) red[tid] += red[tid + off];
        __syncthreads();
    }
    if (tid == 0) bsum[blockIdx.x] = red[0];
}

__global__ __launch_bounds__(1024) void scan_p2_k(int* __restrict__ bsum, int nb) {
    __shared__ int part[1024];
    int tid = threadIdx.x;
    int v = (tid < nb) ? bsum[tid] : 0;
    part[tid] = v;
    __syncthreads();
    for (int off = 1; off < 1024; off <<= 1) {
        int t = (tid >= off) ? part[tid - off] : 0;
        __syncthreads();
        part[tid] += t;
        __syncthreads();
    }
    if (tid < nb) bsum[tid] = part[tid] - v;      // exclusive
}

__global__ void scan_p3_k(const int* __restrict__ deg, const int* __restrict__ bsum,
                          int* __restrict__ rowptr, int* __restrict__ cursor, int n) {
    __shared__ int part[256];
    int tid = threadIdx.x;
    int i = blockIdx.x * 256 + tid;
    int v = (i < n) ? deg[i] : 0;
    part[tid] = v;
    __syncthreads();
    for (int off = 1; off < 256; off <<= 1) {
        int t = (tid >= off) ? part[tid - off] : 0;
        __syncthreads();
        part[tid] += t;
        __syncthreads();
    }
    int excl = part[tid] - v + bsum[blockIdx.x];
    if (i < n) { rowptr[i] = excl; cursor[i] = excl; }
    if (i == n - 1) rowptr[n] = excl + v;
}

__global__ void edge_scatter_k(const int* __restrict__ ei, int E, int n,
                               int* __restrict__ cursor, int* __restrict__ srcs) {
    int i = blockIdx.x * blockDim.x + threadIdx.x;
    if (i >= E + n) return;
    int src, dst;
    if (i < E) { src = ei[i]; dst = ei[E + i]; }
    else       { src = i - E; dst = src; }
    int pos = atomicAdd(&cursor[dst], 1);
    srcs[pos] = src;
}

// ---------------- bf16 split conversions ----------------
__global__ void split_bf16_k(const float* __restrict__ in, u16* __restrict__ hi,
                             u16* __restrict__ lo, int n4) {
    int i = blockIdx.x * 256 + threadIdx.x;
    if (i >= n4) return;
    float4 v = reinterpret_cast<const float4*>(in)[i];
    u16 hx = bf16rn(v.x), hy = bf16rn(v.y), hz = bf16rn(v.z), hw = bf16rn(v.w);
    ushort4 H = make_ushort4(hx, hy, hz, hw);
    ushort4 L = make_ushort4(bf16rn(v.x - bf16f(hx)), bf16rn(v.y - bf16f(hy)),
                             bf16rn(v.z - bf16f(hz)), bf16rn(v.w - bf16f(hw)));
    reinterpret_cast<ushort4*>(hi)[i] = H;
    reinterpret_cast<ushort4*>(lo)[i] = L;
}

// W[K][Nn] row-major -> transposed split Wt[Nn][K] (hi, lo)
__global__ void splitT_bf16_k(const float* __restrict__ W, u16* __restrict__ thi,
                              u16* __restrict__ tlo, int K, int Nn) {
    int idx = blockIdx.x * 256 + threadIdx.x;
    if (idx >= K * Nn) return;
    int k = idx / Nn, nn = idx - k * Nn;
    float v = W[idx];
    u16 h = bf16rn(v);
    u16 l = bf16rn(v - bf16f(h));
    thi[(size_t)nn * K + k] = h;
    tlo[(size_t)nn * K + k] = l;
}

// ---------------- split-bf16 MFMA GEMM, LDS-staged A, fused attn scores ----
template <int NF>
__global__ __launch_bounds__(256) void gemm_lds_k(
        const u16* __restrict__ Ahi, const u16* __restrict__ Alo,
        const u16* __restrict__ Bthi, const u16* __restrict__ Btlo,
        float* __restrict__ C,
        const float* __restrict__ a_src, const float* __restrict__ a_dst,
        float* __restrict__ esrc, float* __restrict__ edst,
        int M, int Nn, int K) {
    __shared__ u16 Ah[2][4][64 * 8];   // [buf][kg][row*8]
    __shared__ u16 Al[2][4][64 * 8];
    const int mb = (M + 63) >> 6;
    const int mi = blockIdx.x % mb;
    const int ni = blockIdx.x / mb;
    const int m0 = mi * 64;
    const int n0 = ni * (NF * 64);
    const int tid = threadIdx.x;
    const int wv = tid >> 6;
    const int lane = tid & 63;
    const int rr = lane & 15;
    const int kg = lane >> 4;

    int srow = m0 + lane; if (srow > M - 1) srow = M - 1;
    const u16* sh = Ahi + (size_t)srow * K + wv * 8;
    const u16* sl = Alo + (size_t)srow * K + wv * 8;

    const u16* pbh[NF];
    const u16* pbl[NF];
#pragma unroll
    for (int nf = 0; nf < NF; ++nf) {
        int col = n0 + (wv * NF + nf) * 16 + rr;
        pbh[nf] = Bthi + (size_t)col * K + kg * 8;
        pbl[nf] = Btlo + (size_t)col * K + kg * 8;
    }

    f32x4 acc[4][NF];
#pragma unroll
    for (int mf = 0; mf < 4; ++mf)
#pragma unroll
        for (int nf = 0; nf < NF; ++nf) acc[mf][nf] = (f32x4){0.f, 0.f, 0.f, 0.f};

    bf16x8 bhc[NF], blc[NF], bhn[NF], bln[NF];
#pragma unroll
    for (int nf = 0; nf < NF; ++nf) {
        bhc[nf] = *reinterpret_cast<const bf16x8*>(pbh[nf]);
        blc[nf] = *reinterpret_cast<const bf16x8*>(pbl[nf]);
    }
    gload16(sh, &Ah[0][wv][0]);
    gload16(sl, &Al[0][wv][0]);
    __syncthreads();

    const int NT = K >> 5;
    for (int t = 0; t < NT; ++t) {
        const int cur = t & 1;
        if (t + 1 < NT) {
            const int kc = (t + 1) << 5;
#pragma unroll
            for (int nf = 0; nf < NF; ++nf) {
                bhn[nf] = *reinterpret_cast<const bf16x8*>(pbh[nf] + kc);
                bln[nf] = *reinterpret_cast<const bf16x8*>(pbl[nf] + kc);
            }
            gload16(sh + kc, &Ah[cur ^ 1][wv][0]);
            gload16(sl + kc, &Al[cur ^ 1][wv][0]);
        }
        bf16x8 ah[4], al[4];
#pragma unroll
        for (int mf = 0; mf < 4; ++mf) {
            ah[mf] = *reinterpret_cast<const bf16x8*>(&Ah[cur][kg][(mf * 16 + rr) * 8]);
            al[mf] = *reinterpret_cast<const bf16x8*>(&Al[cur][kg][(mf * 16 + rr) * 8]);
        }
#pragma unroll
        for (int mf = 0; mf < 4; ++mf)
#pragma unroll
            for (int nf = 0; nf < NF; ++nf) {
                acc[mf][nf] = __builtin_amdgcn_mfma_f32_16x16x32_bf16(ah[mf], bhc[nf], acc[mf][nf], 0, 0, 0);
                acc[mf][nf] = __builtin_amdgcn_mfma_f32_16x16x32_bf16(ah[mf], blc[nf], acc[mf][nf], 0, 0, 0);
                acc[mf][nf] = __builtin_amdgcn_mfma_f32_16x16x32_bf16(al[mf], bhc[nf], acc[mf][nf], 0, 0, 0);
            }
#pragma unroll
        for (int nf = 0; nf < NF; ++nf) { bhc[nf] = bhn[nf]; blc[nf] = bln[nf]; }
        __syncthreads();
    }

    // ---- C store (head-major) ----
#pragma unroll
    for (int mf = 0; mf < 4; ++mf)
#pragma unroll
        for (int nf = 0; nf < NF; ++nf) {
            int col = n0 + (wv * NF + nf) * 16 + rr;
            float* cb = C + ((size_t)(col >> 6) * M) * 64 + (col & 63);
#pragma unroll
            for (int rg = 0; rg < 4; ++rg) {
                int row = m0 + mf * 16 + kg * 4 + rg;
                if (row < M) cb[(size_t)row * 64] = acc[mf][nf][rg];
            }
        }

    // ---- fused attention scores: per-row dot with a_src / a_dst ----
    float asv[NF], adv[NF];
#pragma unroll
    for (int nf = 0; nf < NF; ++nf) {
        int col = n0 + (wv * NF + nf) * 16 + rr;
        asv[nf] = a_src[col];
        adv[nf] = a_dst[col];
    }
    float ps[4][4], pd[4][4];   // [mf][rg]
#pragma unroll
    for (int mf = 0; mf < 4; ++mf)
#pragma unroll
        for (int rg = 0; rg < 4; ++rg) {
            float s = 0.f, dvv = 0.f;
#pragma unroll
            for (int nf = 0; nf < NF; ++nf) {
                s = fmaf(acc[mf][nf][rg], asv[nf], s);
                dvv = fmaf(acc[mf][nf][rg], adv[nf], dvv);
            }
#pragma unroll
            for (int off = 1; off < 16; off <<= 1) {
                s += __shfl_xor(s, off);
                dvv += __shfl_xor(dvv, off);
            }
            ps[mf][rg] = s;
            pd[mf][rg] = dvv;
        }
    // cross-wave combine via LDS (reuse Ah; all reads of it completed)
    float* sm_src = (float*)&Ah[0][0][0];     // [4 waves][64 rows]
    float* sm_dst = sm_src + 256;
    if (rr == 0) {
#pragma unroll
        for (int mf = 0; mf < 4; ++mf)
#pragma unroll
            for (int rg = 0; rg < 4; ++rg) {
                int rl = mf * 16 + kg * 4 + rg;
                sm_src[wv * 64 + rl] = ps[mf][rg];
                sm_dst[wv * 64 + rl] = pd[mf][rg];
            }
    }
    __syncthreads();
    if (tid < 64) {
        int row = m0 + tid;
        if (row < M) {
            const int HTOT = Nn >> 6;
            constexpr int WPH = 4 / NF;        // waves per head
#pragma unroll
            for (int hl = 0; hl < NF; ++hl) {
                float es = 0.f, edv = 0.f;
#pragma unroll
                for (int w = 0; w < WPH; ++w) {
                    es += sm_src[(hl * WPH + w) * 64 + tid];
                    edv += sm_dst[(hl * WPH + w) * 64 + tid];
                }
                int hg = ni * NF + hl;
                esrc[(size_t)row * HTOT + hg] = es;
                edst[(size_t)row * HTOT + hg] = edv;
            }
        }
    }
}

// ---------------- aggregate helpers ----------------
#define ROWQ(SW, J, HB) \
    (*reinterpret_cast<const float4*>(&HB[(size_t)SW[(J) + es].x * 64 + cq * 4]))

#define FMA4(ACC, WK, R) \
    ACC.x = fmaf(WK, R.x, ACC.x); ACC.y = fmaf(WK, R.y, ACC.y); \
    ACC.z = fmaf(WK, R.z, ACC.z); ACC.w = fmaf(WK, R.w, ACC.w);

#define STEPK(SW, CNT, K, R, ACC) \
    if (CNT > 4 * (K)) { float wk_ = __int_as_float(SW[4 * (K) + es].y); FMA4(ACC, wk_, R) }

// generic one-chunk processor (rare path: chunks beyond the first 64 edges)
__device__ __forceinline__ void agg_chunk(const float* __restrict__ hb,
        const float* __restrict__ esrc, int hstride, int hh, float ed,
        const int* __restrict__ srcs, int base, int hi, int2* swv,
        int lane, int es, int cq, float4& acc, float& den) {
    int cnt = min(64, hi - base);
    int idx = base + lane;
    int s = srcs[(idx < hi) ? idx : base];
    swv[lane].x = s;
    float4 z = make_float4(0.f, 0.f, 0.f, 0.f);
    float4 r0 = z, r1 = z, r2 = z, r3 = z, r4 = z, r5 = z, r6 = z, r7 = z;
    r0 = ROWQ(swv, 0, hb);
    if (cnt > 4)  r1 = ROWQ(swv, 4, hb);
    if (cnt > 8)  r2 = ROWQ(swv, 8, hb);
    if (cnt > 12) r3 = ROWQ(swv, 12, hb);
    if (cnt > 16) r4 = ROWQ(swv, 16, hb);
    if (cnt > 20) r5 = ROWQ(swv, 20, hb);
    if (cnt > 24) r6 = ROWQ(swv, 24, hb);
    if (cnt > 28) r7 = ROWQ(swv, 28, hb);
    float e = esrc[s * hstride + hh] + ed;
    e = (e >= 0.f) ? e : 0.2f * e;
    float w = (lane < cnt) ? __expf(e) : 0.f;
    float ws = w;
#pragma unroll
    for (int off = 1; off < 64; off <<= 1) ws += __shfl_xor(ws, off);
    den += ws;
    swv[lane].y = __float_as_int(w);
    STEPK(swv, cnt, 0, r0, acc) STEPK(swv, cnt, 1, r1, acc)
    STEPK(swv, cnt, 2, r2, acc) STEPK(swv, cnt, 3, r3, acc)
    STEPK(swv, cnt, 4, r4, acc) STEPK(swv, cnt, 5, r5, acc)
    STEPK(swv, cnt, 6, r6, acc) STEPK(swv, cnt, 7, r7, acc)
    if (cnt > 32) {
        r0 = ROWQ(swv, 32, hb);
        if (cnt > 36) r1 = ROWQ(swv, 36, hb);
        if (cnt > 40) r2 = ROWQ(swv, 40, hb);
        if (cnt > 44) r3 = ROWQ(swv, 44, hb);
        if (cnt > 48) r4 = ROWQ(swv, 48, hb);
        if (cnt > 52) r5 = ROWQ(swv, 52, hb);
        if (cnt > 56) r6 = ROWQ(swv, 56, hb);
        if (cnt > 60) r7 = ROWQ(swv, 60, hb);
        STEPK(swv, cnt, 8, r0, acc)  STEPK(swv, cnt, 9, r1, acc)
        STEPK(swv, cnt, 10, r2, acc) STEPK(swv, cnt, 11, r3, acc)
        STEPK(swv, cnt, 12, r4, acc) STEPK(swv, cnt, 13, r5, acc)
        STEPK(swv, cnt, 14, r6, acc) STEPK(swv, cnt, 15, r7, acc)
    }
}

// ---------------- GAT aggregation, head-split, 2 dsts per wave -------------
// hm head-major [4][n][64]. Wave handles d0,d1; both srcs loads issued first,
// then both row batches (up to 16 gathers in flight), then both weight phases.
__global__ __launch_bounds__(256) void gat_aggregate_hm2_k(
        const float* __restrict__ hm, const float* __restrict__ esrc,
        const float* __restrict__ edst, const int* __restrict__ rowptr,
        const int* __restrict__ srcs, const float* __restrict__ bias,
        u16* __restrict__ ghi, u16* __restrict__ glo, int n) {
    __shared__ int2 swb[4][128];
    int wv = threadIdx.x >> 6;
    int lane = threadIdx.x & 63;
    int hh = blockIdx.y;                        // head
    int d0 = blockIdx.x * 8 + wv * 2;
    int d1 = d0 + 1;
    if (d0 >= n) return;                        // wave-uniform
    bool v1 = d1 < n;
    const float* hbase = hm + (size_t)hh * n * 64;
    const int es = lane >> 4;
    const int cq = lane & 15;
    int2* sw0 = swb[wv];
    int2* sw1 = swb[wv] + 64;
    int lo0 = rowptr[d0], hi0 = rowptr[d0 + 1];
    int hi1 = v1 ? rowptr[d0 + 2] : hi0;
    int lo1 = hi0;
    int cnt0 = min(64, hi0 - lo0);
    int cnt1 = v1 ? min(64, hi1 - lo1) : 0;
    float ed0 = edst[d0 * 4 + hh];
    float ed1 = v1 ? edst[d1 * 4 + hh] : 0.f;
    // both srcs loads issued back-to-back
    int i0 = lo0 + lane;
    int s0 = srcs[(i0 < hi0) ? i0 : lo0];
    int i1 = lo1 + lane;
    int s1 = (cnt1 > 0) ? srcs[(i1 < hi1) ? i1 : lo1] : 0;
    sw0[lane].x = s0;
    sw1[lane].x = s1;
    // both row batches issued before any weight math
    float4 z = make_float4(0.f, 0.f, 0.f, 0.f);
    float4 a0 = z, a1 = z, a2 = z, a3 = z, a4 = z, a5 = z, a6 = z, a7 = z;
    float4 b0 = z, b1 = z, b2 = z, b3 = z, b4 = z, b5 = z, b6 = z, b7 = z;
    a0 = ROWQ(sw0, 0, hbase);
    if (cnt0 > 4)  a1 = ROWQ(sw0, 4, hbase);
    if (cnt0 > 8)  a2 = ROWQ(sw0, 8, hbase);
    if (cnt0 > 12) a3 = ROWQ(sw0, 12, hbase);
    if (cnt0 > 16) a4 = ROWQ(sw0, 16, hbase);
    if (cnt0 > 20) a5 = ROWQ(sw0, 20, hbase);
    if (cnt0 > 24) a6 = ROWQ(sw0, 24, hbase);
    if (cnt0 > 28) a7 = ROWQ(sw0, 28, hbase);
    if (cnt1 > 0)  b0 = ROWQ(sw1, 0, hbase);
    if (cnt1 > 4)  b1 = ROWQ(sw1, 4, hbase);
    if (cnt1 > 8)  b2 = ROWQ(sw1, 8, hbase);
    if (cnt1 > 12) b3 = ROWQ(sw1, 12, hbase);
    if (cnt1 > 16) b4 = ROWQ(sw1, 16, hbase);
    if (cnt1 > 20) b5 = ROWQ(sw1, 20, hbase);
    if (cnt1 > 24) b6 = ROWQ(sw1, 24, hbase);
    if (cnt1 > 28) b7 = ROWQ(sw1, 28, hbase);
    // weight phases (esrc gathers overlap the row gathers above)
    float e0 = esrc[s0 * 4 + hh] + ed0;
    e0 = (e0 >= 0.f) ? e0 : 0.2f * e0;
    float w0 = (lane < cnt0) ? __expf(e0) : 0.f;
    float e1 = esrc[s1 * 4 + hh] + ed1;
    e1 = (e1 >= 0.f) ? e1 : 0.2f * e1;
    float w1 = (lane < cnt1) ? __expf(e1) : 0.f;
    float den0 = w0, den1 = w1;
#pragma unroll
    for (int off = 1; off < 64; off <<= 1) {
        den0 += __shfl_xor(den0, off);
        den1 += __shfl_xor(den1, off);
    }
    sw0[lane].y = __float_as_int(w0);
    sw1[lane].y = __float_as_int(w1);
    float4 acc0 = z, acc1 = z;
    STEPK(sw0, cnt0, 0, a0, acc0) STEPK(sw0, cnt0, 1, a1, acc0)
    STEPK(sw0, cnt0, 2, a2, acc0) STEPK(sw0, cnt0, 3, a3, acc0)
    STEPK(sw0, cnt0, 4, a4, acc0) STEPK(sw0, cnt0, 5, a5, acc0)
    STEPK(sw0, cnt0, 6, a6, acc0) STEPK(sw0, cnt0, 7, a7, acc0)
    STEPK(sw1, cnt1, 0, b0, acc1) STEPK(sw1, cnt1, 1, b1, acc1)
    STEPK(sw1, cnt1, 2, b2, acc1) STEPK(sw1, cnt1, 3, b3, acc1)
    STEPK(sw1, cnt1, 4, b4, acc1) STEPK(sw1, cnt1, 5, b5, acc1)
    STEPK(sw1, cnt1, 6, b6, acc1) STEPK(sw1, cnt1, 7, b7, acc1)
    if (cnt0 > 32) {
        a0 = ROWQ(sw0, 32, hbase);
        if (cnt0 > 36) a1 = ROWQ(sw0, 36, hbase);
        if (cnt0 > 40) a2 = ROWQ(sw0, 40, hbase);
        if (cnt0 > 44) a3 = ROWQ(sw0, 44, hbase);
        if (cnt0 > 48) a4 = ROWQ(sw0, 48, hbase);
        if (cnt0 > 52) a5 = ROWQ(sw0, 52, hbase);
        if (cnt0 > 56) a6 = ROWQ(sw0, 56, hbase);
        if (cnt0 > 60) a7 = ROWQ(sw0, 60, hbase);
        STEPK(sw0, cnt0, 8, a0, acc0)  STEPK(sw0, cnt0, 9, a1, acc0)
        STEPK(sw0, cnt0, 10, a2, acc0) STEPK(sw0, cnt0, 11, a3, acc0)
        STEPK(sw0, cnt0, 12, a4, acc0) STEPK(sw0, cnt0, 13, a5, acc0)
        STEPK(sw0, cnt0, 14, a6, acc0) STEPK(sw0, cnt0, 15, a7, acc0)
    }
    if (cnt1 > 32) {
        b0 = ROWQ(sw1, 32, hbase);
        if (cnt1 > 36) b1 = ROWQ(sw1, 36, hbase);
        if (cnt1 > 40) b2 = ROWQ(sw1, 40, hbase);
        if (cnt1 > 44) b3 = ROWQ(sw1, 44, hbase);
        if (cnt1 > 48) b4 = ROWQ(sw1, 48, hbase);
        if (cnt1 > 52) b5 = ROWQ(sw1, 52, hbase);
        if (cnt1 > 56) b6 = ROWQ(sw1, 56, hbase);
        if (cnt1 > 60) b7 = ROWQ(sw1, 60, hbase);
        STEPK(sw1, cnt1, 8, b0, acc1)  STEPK(sw1, cnt1, 9, b1, acc1)
        STEPK(sw1, cnt1, 10, b2, acc1) STEPK(sw1, cnt1, 11, b3, acc1)
        STEPK(sw1, cnt1, 12, b4, acc1) STEPK(sw1, cnt1, 13, b5, acc1)
        STEPK(sw1, cnt1, 14, b6, acc1) STEPK(sw1, cnt1, 15, b7, acc1)
    }
    // chunks beyond 64 edges (rare)
    for (int base = lo0 + 64; base < hi0; base += 64)
        agg_chunk(hbase, esrc, 4, hh, ed0, srcs, base, hi0, sw0, lane, es, cq, acc0, den0);
    for (int base = lo1 + 64; base < hi1; base += 64)
        agg_chunk(hbase, esrc, 4, hh, ed1, srcs, base, hi1, sw1, lane, es, cq, acc1, den1);
    // reduce + writeback
    acc0.x += __shfl_xor(acc0.x, 16); acc0.x += __shfl_xor(acc0.x, 32);
    acc0.y += __shfl_xor(acc0.y, 16); acc0.y += __shfl_xor(acc0.y, 32);
    acc0.z += __shfl_xor(acc0.z, 16); acc0.z += __shfl_xor(acc0.z, 32);
    acc0.w += __shfl_xor(acc0.w, 16); acc0.w += __shfl_xor(acc0.w, 32);
    acc1.x += __shfl_xor(acc1.x, 16); acc1.x += __shfl_xor(acc1.x, 32);
    acc1.y += __shfl_xor(acc1.y, 16); acc1.y += __shfl_xor(acc1.y, 32);
    acc1.z += __shfl_xor(acc1.z, 16); acc1.z += __shfl_xor(acc1.z, 32);
    acc1.w += __shfl_xor(acc1.w, 16); acc1.w += __shfl_xor(acc1.w, 32);
    if (es == 0) {
        int c0 = hh * 64 + cq * 4;
        float4 bv = *reinterpret_cast<const float4*>(&bias[c0]);
        {
            float inv = 1.f / den0;
            float4 o;
            o.x = acc0.x * inv + bv.x;
            o.y = acc0.y * inv + bv.y;
            o.z = acc0.z * inv + bv.z;
            o.w = acc0.w * inv + bv.w;
            o.x = (o.x > 0.f) ? o.x : expm1f(o.x);
            o.y = (o.y > 0.f) ? o.y : expm1f(o.y);
            o.z = (o.z > 0.f) ? o.z : expm1f(o.z);
            o.w = (o.w > 0.f) ? o.w : expm1f(o.w);
            u16 hx = bf16rn(o.x), hy = bf16rn(o.y), hz = bf16rn(o.z), hw = bf16rn(o.w);
            ushort4 H = make_ushort4(hx, hy, hz, hw);
            ushort4 L = make_ushort4(bf16rn(o.x - bf16f(hx)), bf16rn(o.y - bf16f(hy)),
                                     bf16rn(o.z - bf16f(hz)), bf16rn(o.w - bf16f(hw)));
            *reinterpret_cast<ushort4*>(&ghi[(size_t)d0 * 256 + c0]) = H;
            *reinterpret_cast<ushort4*>(&glo[(size_t)d0 * 256 + c0]) = L;
        }
        if (v1) {
            float inv = 1.f / den1;
            float4 o;
            o.x = acc1.x * inv + bv.x;
            o.y = acc1.y * inv + bv.y;
            o.z = acc1.z * inv + bv.z;
            o.w = acc1.w * inv + bv.w;
            o.x = (o.x > 0.f) ? o.x : expm1f(o.x);
            o.y = (o.y > 0.f) ? o.y : expm1f(o.y);
            o.z = (o.z > 0.f) ? o.z : expm1f(o.z);
            o.w = (o.w > 0.f) ? o.w : expm1f(o.w);
            u16 hx = bf16rn(o.x), hy = bf16rn(o.y), hz = bf16rn(o.z), hw = bf16rn(o.w);
            ushort4 H = make_ushort4(hx, hy, hz, hw);
            ushort4 L = make_ushort4(bf16rn(o.x - bf16f(hx)), bf16rn(o.y - bf16f(hy)),
                                     bf16rn(o.z - bf16f(hz)), bf16rn(o.w - bf16f(hw)));
            *reinterpret_cast<ushort4*>(&ghi[(size_t)d1 * 256 + c0]) = H;
            *reinterpret_cast<ushort4*>(&glo[(size_t)d1 * 256 + c0]) = L;
        }
    }
}

// ---------------- layer-3 aggregate (1 head), 2 dsts per wave, fused gate --
__global__ __launch_bounds__(256) void gat_aggregate1_attn2_k(
        const float* __restrict__ hin, const float* __restrict__ esrc,
        const float* __restrict__ edst, const int* __restrict__ rowptr,
        const int* __restrict__ srcs, const float* __restrict__ bias,
        const float* __restrict__ wp, const float* __restrict__ bp,
        float* __restrict__ gout, float* __restrict__ attn, int n) {
    __shared__ int2 swb[4][128];
    int wv = threadIdx.x >> 6;
    int lane = threadIdx.x & 63;
    int d0 = blockIdx.x * 8 + wv * 2;
    int d1 = d0 + 1;
    if (d0 >= n) return;
    bool v1 = d1 < n;
    const int es = lane >> 4;
    const int cq = lane & 15;
    int2* sw0 = swb[wv];
    int2* sw1 = swb[wv] + 64;
    int lo0 = rowptr[d0], hi0 = rowptr[d0 + 1];
    int hi1 = v1 ? rowptr[d0 + 2] : hi0;
    int lo1 = hi0;
    int cnt0 = min(64, hi0 - lo0);
    int cnt1 = v1 ? min(64, hi1 - lo1) : 0;
    float ed0 = edst[d0];
    float ed1 = v1 ? edst[d1] : 0.f;
    int i0 = lo0 + lane;
    int s0 = srcs[(i0 < hi0) ? i0 : lo0];
    int i1 = lo1 + lane;
    int s1 = (cnt1 > 0) ? srcs[(i1 < hi1) ? i1 : lo1] : 0;
    sw0[lane].x = s0;
    sw1[lane].x = s1;
    float4 z = make_float4(0.f, 0.f, 0.f, 0.f);
    float4 a0 = z, a1 = z, a2 = z, a3 = z, a4 = z, a5 = z, a6 = z, a7 = z;
    float4 b0 = z, b1 = z, b2 = z, b3 = z, b4 = z, b5 = z, b6 = z, b7 = z;
    a0 = ROWQ(sw0, 0, hin);
    if (cnt0 > 4)  a1 = ROWQ(sw0, 4, hin);
    if (cnt0 > 8)  a2 = ROWQ(sw0, 8, hin);
    if (cnt0 > 12) a3 = ROWQ(sw0, 12, hin);
    if (cnt0 > 16) a4 = ROWQ(sw0, 16, hin);
    if (cnt0 > 20) a5 = ROWQ(sw0, 20, hin);
    if (cnt0 > 24) a6 = ROWQ(sw0, 24, hin);
    if (cnt0 > 28) a7 = ROWQ(sw0, 28, hin);
    if (cnt1 > 0)  b0 = ROWQ(sw1, 0, hin);
    if (cnt1 > 4)  b1 = ROWQ(sw1, 4, hin);
    if (cnt1 > 8)  b2 = ROWQ(sw1, 8, hin);
    if (cnt1 > 12) b3 = ROWQ(sw1, 12, hin);
    if (cnt1 > 16) b4 = ROWQ(sw1, 16, hin);
    if (cnt1 > 20) b5 = ROWQ(sw1, 20, hin);
    if (cnt1 > 24) b6 = ROWQ(sw1, 24, hin);
    if (cnt1 > 28) b7 = ROWQ(sw1, 28, hin);
    float e0 = esrc[s0] + ed0;
    e0 = (e0 >= 0.f) ? e0 : 0.2f * e0;
    float w0 = (lane < cnt0) ? __expf(e0) : 0.f;
    float e1 = esrc[s1] + ed1;
    e1 = (e1 >= 0.f) ? e1 : 0.2f * e1;
    float w1 = (lane < cnt1) ? __expf(e1) : 0.f;
    float den0 = w0, den1 = w1;
#pragma unroll
    for (int off = 1; off < 64; off <<= 1) {
        den0 += __shfl_xor(den0, off);
        den1 += __shfl_xor(den1, off);
    }
    sw0[lane].y = __float_as_int(w0);
    sw1[lane].y = __float_as_int(w1);
    float4 acc0 = z, acc1 = z;
    STEPK(sw0, cnt0, 0, a0, acc0) STEPK(sw0, cnt0, 1, a1, acc0)
    STEPK(sw0, cnt0, 2, a2, acc0) STEPK(sw0, cnt0, 3, a3, acc0)
    STEPK(sw0, cnt0, 4, a4, acc0) STEPK(sw0, cnt0, 5, a5, acc0)
    STEPK(sw0, cnt0, 6, a6, acc0) STEPK(sw0, cnt0, 7, a7, acc0)
    STEPK(sw1, cnt1, 0, b0, acc1) STEPK(sw1, cnt1, 1, b1, acc1)
    STEPK(sw1, cnt1, 2, b2, acc1) STEPK(sw1, cnt1, 3, b3, acc1)
    STEPK(sw1, cnt1, 4, b4, acc1) STEPK(sw1, cnt1, 5, b5, acc1)
    STEPK(sw1, cnt1, 6, b6, acc1) STEPK(sw1, cnt1, 7, b7, acc1)
    if (cnt0 > 32) {
        a0 = ROWQ(sw0, 32, hin);
        if (cnt0 > 36) a1 = ROWQ(sw0, 36, hin);
        if (cnt0 > 40) a2 = ROWQ(sw0, 40, hin);
        if (cnt0 > 44) a3 = ROWQ(sw0, 44, hin);
        if (cnt0 > 48) a4 = ROWQ(sw0, 48, hin);
        if (cnt0 > 52) a5 = ROWQ(sw0, 52, hin);
        if (cnt0 > 56) a6 = ROWQ(sw0, 56, hin);
        if (cnt0 > 60) a7 = ROWQ(sw0, 60, hin);
        STEPK(sw0, cnt0, 8, a0, acc0)  STEPK(sw0, cnt0, 9, a1, acc0)
        STEPK(sw0, cnt0, 10, a2, acc0) STEPK(sw0, cnt0, 11, a3, acc0)
        STEPK(sw0, cnt0, 12, a4, acc0) STEPK(sw0, cnt0, 13, a5, acc0)
        STEPK(sw0, cnt0, 14, a6, acc0) STEPK(sw0, cnt0, 15, a7, acc0)
    }
    if (cnt1 > 32) {
        b0 = ROWQ(sw1, 32, hin);
        if (cnt1 > 36) b1 = ROWQ(sw1, 36, hin);
        if (cnt1 > 40) b2 = ROWQ(sw1, 40, hin);
        if (cnt1 > 44) b3 = ROWQ(sw1, 44, hin);
        if (cnt1 > 48) b4 = ROWQ(sw1, 48, hin);
        if (cnt1 > 52) b5 = ROWQ(sw1, 52, hin);
        if (cnt1 > 56) b6 = ROWQ(sw1, 56, hin);
        if (cnt1 > 60) b7 = ROWQ(sw1, 60, hin);
        STEPK(sw1, cnt1, 8, b0, acc1)  STEPK(sw1, cnt1, 9, b1, acc1)
        STEPK(sw1, cnt1, 10, b2, acc1) STEPK(sw1, cnt1, 11, b3, acc1)
        STEPK(sw1, cnt1, 12, b4, acc1) STEPK(sw1, cnt1, 13, b5, acc1)
        STEPK(sw1, cnt1, 14, b6, acc1) STEPK(sw1, cnt1, 15, b7, acc1)
    }
    for (int base = lo0 + 64; base < hi0; base += 64)
        agg_chunk(hin, esrc, 1, 0, ed0, srcs, base, hi0, sw0, lane, es, cq, acc0, den0);
    for (int base = lo1 + 64; base < hi1; base += 64)
        agg_chunk(hin, esrc, 1, 0, ed1, srcs, base, hi1, sw1, lane, es, cq, acc1, den1);
    acc0.x += __shfl_xor(acc0.x, 16); acc0.x += __shfl_xor(acc0.x, 32);
    acc0.y += __shfl_xor(acc0.y, 16); acc0.y += __shfl_xor(acc0.y, 32);
    acc0.z += __shfl_xor(acc0.z, 16); acc0.z += __shfl_xor(acc0.z, 32);
    acc0.w += __shfl_xor(acc0.w, 16); acc0.w += __shfl_xor(acc0.w, 32);
    acc1.x += __shfl_xor(acc1.x, 16); acc1.x += __shfl_xor(acc1.x, 32);
    acc1.y += __shfl_xor(acc1.y, 16); acc1.y += __shfl_xor(acc1.y, 32);
    acc1.z += __shfl_xor(acc1.z, 16); acc1.z += __shfl_xor(acc1.z, 32);
    acc1.w += __shfl_xor(acc1.w, 16); acc1.w += __shfl_xor(acc1.w, 32);
    int c0 = cq * 4;
    float4 bv = *reinterpret_cast<const float4*>(&bias[c0]);
    float4 wv4 = *reinterpret_cast<const float4*>(&wp[c0]);
    {
        float inv = 1.f / den0;
        float4 o;
        o.x = acc0.x * inv + bv.x;
        o.y = acc0.y * inv + bv.y;
        o.z = acc0.z * inv + bv.z;
        o.w = acc0.w * inv + bv.w;
        o.x = (o.x > 0.f) ? o.x : expm1f(o.x);
        o.y = (o.y > 0.f) ? o.y : expm1f(o.y);
        o.z = (o.z > 0.f) ? o.z : expm1f(o.z);
        o.w = (o.w > 0.f) ? o.w : expm1f(o.w);
        if (es == 0)
            *reinterpret_cast<float4*>(&gout[(size_t)d0 * 64 + c0]) = o;
        float v = o.x * wv4.x + o.y * wv4.y + o.z * wv4.z + o.w * wv4.w;
#pragma unroll
        for (int off = 1; off < 16; off <<= 1) v += __shfl_xor(v, off);
        if (lane == 0) attn[d0] = 1.f / (1.f + __expf(-(v + bp[0])));
    }
    if (v1) {
        float inv = 1.f / den1;
        float4 o;
        o.x = acc1.x * inv + bv.x;
        o.y = acc1.y * inv + bv.y;
        o.z = acc1.z * inv + bv.z;
        o.w = acc1.w * inv + bv.w;
        o.x = (o.x > 0.f) ? o.x : expm1f(o.x);
        o.y = (o.y > 0.f) ? o.y : expm1f(o.y);
        o.z = (o.z > 0.f) ? o.z : expm1f(o.z);
        o.w = (o.w > 0.f) ? o.w : expm1f(o.w);
        if (es == 0)
            *reinterpret_cast<float4*>(&gout[(size_t)d1 * 64 + c0]) = o;
        float v = o.x * wv4.x + o.y * wv4.y + o.z * wv4.z + o.w * wv4.w;
#pragma unroll
        for (int off = 1; off < 16; off <<= 1) v += __shfl_xor(v, off);
        if (lane == 0) attn[d1] = 1.f / (1.f + __expf(-(v + bp[0])));
    }
}

// ---------------- parallel segmented pooling (batch is sorted) --------------
__global__ void pool_partial_k(const float* __restrict__ g3, const float* __restrict__ attn,
                               const int* __restrict__ batch, int n, float* __restrict__ sums) {
    int wid = blockIdx.x * (blockDim.x >> 6) + (threadIdx.x >> 6);
    int lane = threadIdx.x & 63;
    int nwaves = gridDim.x * (blockDim.x >> 6);
    int per = (n + nwaves - 1) / nwaves;
    int i0 = wid * per;
    int i1 = i0 + per;
    if (i1 > n) i1 = n;
    if (i0 >= i1) return;
    int cur = batch[i0];
    float acc = 0.f;
    for (int i = i0; i < i1; ++i) {
        int b = batch[i];
        if (b != cur) {
            atomicAdd(&sums[cur * 64 + lane], acc);
            acc = 0.f;
            cur = b;
        }
        acc += g3[(size_t)i * 64 + lane] * attn[i];
    }
    atomicAdd(&sums[cur * 64 + lane], acc);
}

// ---------------- final regressor: one block, wave per graph ----------------
__global__ void regress_k(const float* __restrict__ sums, const int* __restrict__ batch, int n,
                          const float* __restrict__ wr, const float* __restrict__ br,
                          float* __restrict__ out, int B) {
    int b = threadIdx.x >> 6;
    int lane = threadIdx.x & 63;
    if (b >= B) return;
    int lo = 0, hi = n;
    while (lo < hi) { int mid = (lo + hi) >> 1; if (batch[mid] < b) lo = mid + 1; else hi = mid; }
    int seg_lo = lo;
    lo = 0; hi = n;
    while (lo < hi) { int mid = (lo + hi) >> 1; if (batch[mid] < b + 1) lo = mid + 1; else hi = mid; }
    float cnt = (float)(lo - seg_lo);
    if (cnt < 1.f) cnt = 1.f;
    float v = (sums[b * 64 + lane] / cnt) * wr[lane];
#pragma unroll
    for (int off = 32; off; off >>= 1) v += __shfl_xor(v, off);
    if (lane == 0) out[b] = v + br[0];
}

// ---------------------------------------------------------------------------
extern "C" void kernel_launch(void* const* d_in, const int* in_sizes, int n_in,
                              void* d_out, int out_size, void* d_ws, size_t ws_size,
                              hipStream_t stream) {
    const float* x   = (const float*)d_in[0];
    const int*   ei  = (const int*)d_in[1];
    const int*   bat = (const int*)d_in[2];
    const float* W1  = (const float*)d_in[3];
    const float* as1 = (const float*)d_in[4];
    const float* ad1 = (const float*)d_in[5];
    const float* b1  = (const float*)d_in[6];
    const float* W2  = (const float*)d_in[7];
    const float* as2 = (const float*)d_in[8];
    const float* ad2 = (const float*)d_in[9];
    const float* b2  = (const float*)d_in[10];
    const float* W3  = (const float*)d_in[11];
    const float* as3 = (const float*)d_in[12];
    const float* ad3 = (const float*)d_in[13];
    const float* b3  = (const float*)d_in[14];
    const float* wp  = (const float*)d_in[15];
    const float* bp  = (const float*)d_in[16];
    const float* wr  = (const float*)d_in[17];
    const float* br  = (const float*)d_in[18];
    float* out = (float*)d_out;

    const int N    = in_sizes[2];          // 20000
    const int E    = in_sizes[1] / 2;      // 320000
    const int DIN  = in_sizes[0] / N;      // 128
    const int Etot = E + N;
    const int Bc   = out_size;             // 16

    char* ws = (char*)d_ws;
    size_t off = 0;
    auto alloc = [&](size_t bytes) {
        void* p = ws + off;
        off = (off + bytes + 255) & ~(size_t)255;
        return p;
    };
    int*   deg    = (int*)alloc((size_t)N * 4);
    int*   rowptr = (int*)alloc((size_t)(N + 1) * 4);
    int*   cursor = (int*)alloc((size_t)N * 4);
    int*   bsum   = (int*)alloc((size_t)1024 * 4);
    int*   srcs   = (int*)alloc((size_t)Etot * 4);
    float* bufA   = (float*)alloc((size_t)N * 256 * 4);     // GEMM out h (head-major)
    u16*   Ahi    = (u16*)alloc((size_t)N * 256 * 2);       // x/g split hi
    u16*   Alo    = (u16*)alloc((size_t)N * 256 * 2);       // x/g split lo
    float* h3     = (float*)alloc((size_t)N * 64 * 4);
    float* g3     = (float*)alloc((size_t)N * 64 * 4);
    float* esrc   = (float*)alloc((size_t)N * 4 * 4);
    float* edst   = (float*)alloc((size_t)N * 4 * 4);
    float* attn   = (float*)alloc((size_t)N * 4);
    float* sums   = (float*)alloc((size_t)Bc * 64 * 4);
    u16*   w1hi   = (u16*)alloc((size_t)256 * DIN * 2);
    u16*   w1lo   = (u16*)alloc((size_t)256 * DIN * 2);
    u16*   w2hi   = (u16*)alloc((size_t)256 * 256 * 2);
    u16*   w2lo   = (u16*)alloc((size_t)256 * 256 * 2);
    u16*   w3hi   = (u16*)alloc((size_t)64 * 256 * 2);
    u16*   w3lo   = (u16*)alloc((size_t)64 * 256 * 2);
    (void)ws_size;

    // CSR build (shared by all layers); hierarchical parallel scan
    hipMemsetAsync(deg, 0, (size_t)N * 4, stream);
    int eb = (Etot + 255) / 256;
    int nb = (N + 255) / 256;              // 79 blocks <= 1024
    edge_hist_k<<<eb, 256, 0, stream>>>(ei, E, N, deg);
    scan_p1_k<<<nb, 256, 0, stream>>>(deg, bsum, N);
    scan_p2_k<<<1, 1024, 0, stream>>>(bsum, nb);
    scan_p3_k<<<nb, 256, 0, stream>>>(deg, bsum, rowptr, cursor, N);
    edge_scatter_k<<<eb, 256, 0, stream>>>(ei, E, N, cursor, srcs);

    // weight splits (transposed) + x split
    splitT_bf16_k<<<(DIN * 256 + 255) / 256, 256, 0, stream>>>(W1, w1hi, w1lo, DIN, 256);
    splitT_bf16_k<<<(256 * 256 + 255) / 256, 256, 0, stream>>>(W2, w2hi, w2lo, 256, 256);
    splitT_bf16_k<<<(256 * 64 + 255) / 256, 256, 0, stream>>>(W3, w3hi, w3lo, 256, 64);
    split_bf16_k<<<(N * DIN / 4 + 255) / 256, 256, 0, stream>>>(x, Ahi, Alo, N * DIN / 4);

    const int mb = (N + 63) / 64;          // 313
    int nb8 = (N + 7) / 8;
    dim3 agg_grid(nb8, 4);

    // Layer 1: DIN -> (4,64) concat      (BN=128 -> 2 n-tiles)
    gemm_lds_k<2><<<mb * 2, 256, 0, stream>>>(Ahi, Alo, w1hi, w1lo, bufA, as1, ad1, esrc, edst, N, 256, DIN);
    gat_aggregate_hm2_k<<<agg_grid, 256, 0, stream>>>(bufA, esrc, edst, rowptr, srcs, b1, Ahi, Alo, N);

    // Layer 2: 256 -> (4,64) concat
    gemm_lds_k<2><<<mb * 2, 256, 0, stream>>>(Ahi, Alo, w2hi, w2lo, bufA, as2, ad2, esrc, edst, N, 256, 256);
    gat_aggregate_hm2_k<<<agg_grid, 256, 0, stream>>>(bufA, esrc, edst, rowptr, srcs, b2, Ahi, Alo, N);

    // Layer 3: 256 -> (1,64) mean + fused node-attention gate   (BN=64)
    gemm_lds_k<1><<<mb, 256, 0, stream>>>(Ahi, Alo, w3hi, w3lo, h3, as3, ad3, esrc, edst, N, 64, 256);
    gat_aggregate1_attn2_k<<<nb8, 256, 0, stream>>>(h3, esrc, edst, rowptr, srcs, b3, wp, bp, g3, attn, N);

    // Attention pool + regressor (parallel)
    hipMemsetAsync(sums, 0, (size_t)Bc * 64 * 4, stream);
    pool_partial_k<<<256, 256, 0, stream>>>(g3, attn, bat, N, sums);
    regress_k<<<1, 1024, 0, stream>>>(sums, bat, N, wr, br, out, Bc);
}

// Round 17
// 245.343 us; speedup vs baseline: 1.2492x; 1.0984x over previous
//
#include <hip/hip_runtime.h>

// ---------------------------------------------------------------------------
// GAT (3 layers) + attention pooling + regressor.  [round-14 best: 245.7us]
// GEMMs: split-bf16 MFMA (a_hi+a_lo, 3 products, f32 accum), A staged in LDS
// via global_load_lds; attn scores fused into GEMM epilogue; h stored
// HEAD-MAJOR [H][N][64] (5.1MB/head gather set).
// Aggregates: latency-overlapped — src published to LDS first, ALL row loads
// issued before the weight phase (gathers overlap exp/reduce), 4-edge static
// steps with w=0 padding (no clamps in hot path).
// Aggregate floor ~47.7us is gather-latency x per-CU-concurrency bound
// (FETCH-insensitive: 148->90MB left duration unchanged).
// N=20000 nodes, E=320000 edges (+N self loops), H=4 heads, C=64, B=16 graphs.
// ---------------------------------------------------------------------------

typedef unsigned short u16;
typedef __attribute__((ext_vector_type(8))) short bf16x8;
typedef __attribute__((ext_vector_type(4))) float f32x4;

__device__ __forceinline__ u16 bf16rn(float x) {
    unsigned u = __float_as_uint(x);
    u += 0x7FFFu + ((u >> 16) & 1u);
    return (u16)(u >> 16);
}
__device__ __forceinline__ float bf16f(u16 h) {
    return __uint_as_float(((unsigned)h) << 16);
}

__device__ __forceinline__ void gload16(const u16* g, u16* l) {
    __builtin_amdgcn_global_load_lds(
        (const __attribute__((address_space(1))) unsigned int*)g,
        (__attribute__((address_space(3))) unsigned int*)l, 16, 0, 0);
}

// ---------------- CSR-by-destination build ----------------
__global__ void edge_hist_k(const int* __restrict__ ei, int E, int n, int* __restrict__ deg) {
    int i = blockIdx.x * blockDim.x + threadIdx.x;
    if (i >= E + n) return;
    int dst = (i < E) ? ei[E + i] : (i - E);   // self-loop for i >= E
    atomicAdd(&deg[dst], 1);
}

// 3-pass hierarchical exclusive scan
__global__ void scan_p1_k(const int* __restrict__ deg, int* __restrict__ bsum, int n) {
    __shared__ int red[256];
    int tid = threadIdx.x;
    int i = blockIdx.x * 256 + tid;
    int v = (i < n) ? deg[i] : 0;
    red[tid] = v;
    __syncthreads();
    for (int off = 128; off; off >>= 1) {
        if (tid < off) red[tid] += red[tid + off];
        __syncthreads();
    }
    if (tid == 0) bsum[blockIdx.x] = red[0];
}

__global__ __launch_bounds__(1024) void scan_p2_k(int* __restrict__ bsum, int nb) {
    __shared__ int part[1024];
    int tid = threadIdx.x;
    int v = (tid < nb) ? bsum[tid] : 0;
    part[tid] = v;
    __syncthreads();
    for (int off = 1; off < 1024; off <<= 1) {
        int t = (tid >= off) ? part[tid - off] : 0;
        __syncthreads();
        part[tid] += t;
        __syncthreads();
    }
    if (tid < nb) bsum[tid] = part[tid] - v;      // exclusive
}

__global__ void scan_p3_k(const int* __restrict__ deg, const int* __restrict__ bsum,
                          int* __restrict__ rowptr, int* __restrict__ cursor, int n) {
    __shared__ int part[256];
    int tid = threadIdx.x;
    int i = blockIdx.x * 256 + tid;
    int v = (i < n) ? deg[i] : 0;
    part[tid] = v;
    __syncthreads();
    for (int off = 1; off < 256; off <<= 1) {
        int t = (tid >= off) ? part[tid - off] : 0;
        __syncthreads();
        part[tid] += t;
        __syncthreads();
    }
    int excl = part[tid] - v + bsum[blockIdx.x];
    if (i < n) { rowptr[i] = excl; cursor[i] = excl; }
    if (i == n - 1) rowptr[n] = excl + v;
}

__global__ void edge_scatter_k(const int* __restrict__ ei, int E, int n,
                               int* __restrict__ cursor, int* __restrict__ srcs) {
    int i = blockIdx.x * blockDim.x + threadIdx.x;
    if (i >= E + n) return;
    int src, dst;
    if (i < E) { src = ei[i]; dst = ei[E + i]; }
    else       { src = i - E; dst = src; }
    int pos = atomicAdd(&cursor[dst], 1);
    srcs[pos] = src;
}

// ---------------- bf16 split conversions ----------------
__global__ void split_bf16_k(const float* __restrict__ in, u16* __restrict__ hi,
                             u16* __restrict__ lo, int n4) {
    int i = blockIdx.x * 256 + threadIdx.x;
    if (i >= n4) return;
    float4 v = reinterpret_cast<const float4*>(in)[i];
    u16 hx = bf16rn(v.x), hy = bf16rn(v.y), hz = bf16rn(v.z), hw = bf16rn(v.w);
    ushort4 H = make_ushort4(hx, hy, hz, hw);
    ushort4 L = make_ushort4(bf16rn(v.x - bf16f(hx)), bf16rn(v.y - bf16f(hy)),
                             bf16rn(v.z - bf16f(hz)), bf16rn(v.w - bf16f(hw)));
    reinterpret_cast<ushort4*>(hi)[i] = H;
    reinterpret_cast<ushort4*>(lo)[i] = L;
}

// W[K][Nn] row-major -> transposed split Wt[Nn][K] (hi, lo)
__global__ void splitT_bf16_k(const float* __restrict__ W, u16* __restrict__ thi,
                              u16* __restrict__ tlo, int K, int Nn) {
    int idx = blockIdx.x * 256 + threadIdx.x;
    if (idx >= K * Nn) return;
    int k = idx / Nn, nn = idx - k * Nn;
    float v = W[idx];
    u16 h = bf16rn(v);
    u16 l = bf16rn(v - bf16f(h));
    thi[(size_t)nn * K + k] = h;
    tlo[(size_t)nn * K + k] = l;
}

// ---------------- split-bf16 MFMA GEMM, LDS-staged A, fused attn scores ----
// C emitted HEAD-MAJOR: C[((col>>6)*M + row)*64 + (col&63)].
// Epilogue also emits esrc/edst [M][Nn/64]: per-row dot with a_src/a_dst.
template <int NF>
__global__ __launch_bounds__(256) void gemm_lds_k(
        const u16* __restrict__ Ahi, const u16* __restrict__ Alo,
        const u16* __restrict__ Bthi, const u16* __restrict__ Btlo,
        float* __restrict__ C,
        const float* __restrict__ a_src, const float* __restrict__ a_dst,
        float* __restrict__ esrc, float* __restrict__ edst,
        int M, int Nn, int K) {
    __shared__ u16 Ah[2][4][64 * 8];   // [buf][kg][row*8]
    __shared__ u16 Al[2][4][64 * 8];
    const int mb = (M + 63) >> 6;
    const int mi = blockIdx.x % mb;
    const int ni = blockIdx.x / mb;
    const int m0 = mi * 64;
    const int n0 = ni * (NF * 64);
    const int tid = threadIdx.x;
    const int wv = tid >> 6;
    const int lane = tid & 63;
    const int rr = lane & 15;
    const int kg = lane >> 4;

    int srow = m0 + lane; if (srow > M - 1) srow = M - 1;
    const u16* sh = Ahi + (size_t)srow * K + wv * 8;
    const u16* sl = Alo + (size_t)srow * K + wv * 8;

    const u16* pbh[NF];
    const u16* pbl[NF];
#pragma unroll
    for (int nf = 0; nf < NF; ++nf) {
        int col = n0 + (wv * NF + nf) * 16 + rr;
        pbh[nf] = Bthi + (size_t)col * K + kg * 8;
        pbl[nf] = Btlo + (size_t)col * K + kg * 8;
    }

    f32x4 acc[4][NF];
#pragma unroll
    for (int mf = 0; mf < 4; ++mf)
#pragma unroll
        for (int nf = 0; nf < NF; ++nf) acc[mf][nf] = (f32x4){0.f, 0.f, 0.f, 0.f};

    bf16x8 bhc[NF], blc[NF], bhn[NF], bln[NF];
#pragma unroll
    for (int nf = 0; nf < NF; ++nf) {
        bhc[nf] = *reinterpret_cast<const bf16x8*>(pbh[nf]);
        blc[nf] = *reinterpret_cast<const bf16x8*>(pbl[nf]);
    }
    gload16(sh, &Ah[0][wv][0]);
    gload16(sl, &Al[0][wv][0]);
    __syncthreads();

    const int NT = K >> 5;
    for (int t = 0; t < NT; ++t) {
        const int cur = t & 1;
        if (t + 1 < NT) {
            const int kc = (t + 1) << 5;
#pragma unroll
            for (int nf = 0; nf < NF; ++nf) {
                bhn[nf] = *reinterpret_cast<const bf16x8*>(pbh[nf] + kc);
                bln[nf] = *reinterpret_cast<const bf16x8*>(pbl[nf] + kc);
            }
            gload16(sh + kc, &Ah[cur ^ 1][wv][0]);
            gload16(sl + kc, &Al[cur ^ 1][wv][0]);
        }
        bf16x8 ah[4], al[4];
#pragma unroll
        for (int mf = 0; mf < 4; ++mf) {
            ah[mf] = *reinterpret_cast<const bf16x8*>(&Ah[cur][kg][(mf * 16 + rr) * 8]);
            al[mf] = *reinterpret_cast<const bf16x8*>(&Al[cur][kg][(mf * 16 + rr) * 8]);
        }
#pragma unroll
        for (int mf = 0; mf < 4; ++mf)
#pragma unroll
            for (int nf = 0; nf < NF; ++nf) {
                acc[mf][nf] = __builtin_amdgcn_mfma_f32_16x16x32_bf16(ah[mf], bhc[nf], acc[mf][nf], 0, 0, 0);
                acc[mf][nf] = __builtin_amdgcn_mfma_f32_16x16x32_bf16(ah[mf], blc[nf], acc[mf][nf], 0, 0, 0);
                acc[mf][nf] = __builtin_amdgcn_mfma_f32_16x16x32_bf16(al[mf], bhc[nf], acc[mf][nf], 0, 0, 0);
            }
#pragma unroll
        for (int nf = 0; nf < NF; ++nf) { bhc[nf] = bhn[nf]; blc[nf] = bln[nf]; }
        __syncthreads();
    }

    // ---- C store (head-major) ----
#pragma unroll
    for (int mf = 0; mf < 4; ++mf)
#pragma unroll
        for (int nf = 0; nf < NF; ++nf) {
            int col = n0 + (wv * NF + nf) * 16 + rr;
            float* cb = C + ((size_t)(col >> 6) * M) * 64 + (col & 63);
#pragma unroll
            for (int rg = 0; rg < 4; ++rg) {
                int row = m0 + mf * 16 + kg * 4 + rg;
                if (row < M) cb[(size_t)row * 64] = acc[mf][nf][rg];
            }
        }

    // ---- fused attention scores: per-row dot with a_src / a_dst ----
    float asv[NF], adv[NF];
#pragma unroll
    for (int nf = 0; nf < NF; ++nf) {
        int col = n0 + (wv * NF + nf) * 16 + rr;
        asv[nf] = a_src[col];
        adv[nf] = a_dst[col];
    }
    float ps[4][4], pd[4][4];   // [mf][rg]
#pragma unroll
    for (int mf = 0; mf < 4; ++mf)
#pragma unroll
        for (int rg = 0; rg < 4; ++rg) {
            float s = 0.f, dvv = 0.f;
#pragma unroll
            for (int nf = 0; nf < NF; ++nf) {
                s = fmaf(acc[mf][nf][rg], asv[nf], s);
                dvv = fmaf(acc[mf][nf][rg], adv[nf], dvv);
            }
#pragma unroll
            for (int off = 1; off < 16; off <<= 1) {
                s += __shfl_xor(s, off);
                dvv += __shfl_xor(dvv, off);
            }
            ps[mf][rg] = s;
            pd[mf][rg] = dvv;
        }
    // cross-wave combine via LDS (reuse Ah; all reads of it completed)
    float* sm_src = (float*)&Ah[0][0][0];     // [4 waves][64 rows]
    float* sm_dst = sm_src + 256;
    if (rr == 0) {
#pragma unroll
        for (int mf = 0; mf < 4; ++mf)
#pragma unroll
            for (int rg = 0; rg < 4; ++rg) {
                int rl = mf * 16 + kg * 4 + rg;
                sm_src[wv * 64 + rl] = ps[mf][rg];
                sm_dst[wv * 64 + rl] = pd[mf][rg];
            }
    }
    __syncthreads();
    if (tid < 64) {
        int row = m0 + tid;
        if (row < M) {
            const int HTOT = Nn >> 6;
            constexpr int WPH = 4 / NF;        // waves per head
#pragma unroll
            for (int hl = 0; hl < NF; ++hl) {
                float es = 0.f, edv = 0.f;
#pragma unroll
                for (int w = 0; w < WPH; ++w) {
                    es += sm_src[(hl * WPH + w) * 64 + tid];
                    edv += sm_dst[(hl * WPH + w) * 64 + tid];
                }
                int hg = ni * NF + hl;
                esrc[(size_t)row * HTOT + hg] = es;
                edst[(size_t)row * HTOT + hg] = edv;
            }
        }
    }
}

// ---------------- GAT aggregation, head-split, latency-overlapped ----------
// Wave per (dst,head); lane = (es=lane>>4, cq=lane&15). Per 64-edge chunk:
// publish src to LDS, issue ALL row loads (up to 16, covering 64 slots),
// THEN weight phase (overlaps gathers). Padded lanes wrote w=0 -> static
// 4-edge STEPs need no clamps.
#define AGG_STEP(K, RK)                                                        \
    if (cnt > 4 * K) {                                                         \
        float wk = __int_as_float(swv[4 * K + es].y);                          \
        acc.x = fmaf(wk, RK.x, acc.x); acc.y = fmaf(wk, RK.y, acc.y);          \
        acc.z = fmaf(wk, RK.z, acc.z); acc.w = fmaf(wk, RK.w, acc.w);          \
    }

__global__ __launch_bounds__(256) void gat_aggregate_hm_k(
        const float* __restrict__ hm, const float* __restrict__ esrc,
        const float* __restrict__ edst, const int* __restrict__ rowptr,
        const int* __restrict__ srcs, const float* __restrict__ bias,
        u16* __restrict__ ghi, u16* __restrict__ glo, int n) {
    __shared__ int2 swb[4][64];
    int wv = threadIdx.x >> 6;
    int d = blockIdx.x * 4 + wv;
    int lane = threadIdx.x & 63;
    int hh = blockIdx.y;                        // head
    if (d >= n) return;
    const float* hbase = hm + (size_t)hh * n * 64;
    const int es = lane >> 4;                   // edge sub-slot 0..3
    const int cq = lane & 15;                   // channel quad
    int2* swv = swb[wv];
    float ed = edst[d * 4 + hh];
    int lo = rowptr[d], hi = rowptr[d + 1];
    float4 acc = make_float4(0.f, 0.f, 0.f, 0.f);
    float den = 0.f;
    for (int base = lo; base < hi; base += 64) {
        int cnt = min(64, hi - base);
        int idx = base + lane;
        int s = srcs[(idx < hi) ? idx : lo];
        swv[lane].x = s;                        // publish src EARLY (same-wave LDS)
        auto ROWL = [&](int j) -> float4 {      // j < 64 always valid (padded s ok)
            int sp = swv[j].x;
            return *reinterpret_cast<const float4*>(&hbase[(size_t)sp * 64 + cq * 4]);
        };
        float4 z = make_float4(0.f, 0.f, 0.f, 0.f);
        float4 r0 = z, r1 = z, r2 = z, r3 = z, r4 = z, r5 = z, r6 = z, r7 = z;
        // issue all row loads BEFORE the weight phase (gathers overlap exp/reduce)
        r0 = ROWL(es);
        if (cnt > 4)  r1 = ROWL(4 + es);
        if (cnt > 8)  r2 = ROWL(8 + es);
        if (cnt > 12) r3 = ROWL(12 + es);
        if (cnt > 16) r4 = ROWL(16 + es);
        if (cnt > 20) r5 = ROWL(20 + es);
        if (cnt > 24) r6 = ROWL(24 + es);
        if (cnt > 28) r7 = ROWL(28 + es);
        // weight phase (overlaps in-flight gathers)
        float e = esrc[s * 4 + hh] + ed;
        e = (e >= 0.f) ? e : 0.2f * e;          // leaky_relu(0.2)
        float w = (lane < cnt) ? __expf(e) : 0.f;
        float ws = w;
#pragma unroll
        for (int off = 1; off < 64; off <<= 1) ws += __shfl_xor(ws, off);
        den += ws;
        swv[lane].y = __float_as_int(w);        // padded lanes publish w=0
        AGG_STEP(0, r0) AGG_STEP(1, r1) AGG_STEP(2, r2) AGG_STEP(3, r3)
        AGG_STEP(4, r4) AGG_STEP(5, r5) AGG_STEP(6, r6) AGG_STEP(7, r7)
        if (cnt > 32) {                         // rare (deg>32)
            r0 = ROWL(32 + es);
            if (cnt > 36) r1 = ROWL(36 + es);
            if (cnt > 40) r2 = ROWL(40 + es);
            if (cnt > 44) r3 = ROWL(44 + es);
            if (cnt > 48) r4 = ROWL(48 + es);
            if (cnt > 52) r5 = ROWL(52 + es);
            if (cnt > 56) r6 = ROWL(56 + es);
            if (cnt > 60) r7 = ROWL(60 + es);
            AGG_STEP(8, r0)  AGG_STEP(9, r1)  AGG_STEP(10, r2) AGG_STEP(11, r3)
            AGG_STEP(12, r4) AGG_STEP(13, r5) AGG_STEP(14, r6) AGG_STEP(15, r7)
        }
    }
    // combine the 4 edge sub-slots (lanes differing in bits 4,5)
    acc.x += __shfl_xor(acc.x, 16); acc.x += __shfl_xor(acc.x, 32);
    acc.y += __shfl_xor(acc.y, 16); acc.y += __shfl_xor(acc.y, 32);
    acc.z += __shfl_xor(acc.z, 16); acc.z += __shfl_xor(acc.z, 32);
    acc.w += __shfl_xor(acc.w, 16); acc.w += __shfl_xor(acc.w, 32);
    if (es == 0) {
        int c0 = hh * 64 + cq * 4;
        float inv = 1.f / den;
        float4 bv = *reinterpret_cast<const float4*>(&bias[c0]);
        float4 o;
        o.x = acc.x * inv + bv.x;
        o.y = acc.y * inv + bv.y;
        o.z = acc.z * inv + bv.z;
        o.w = acc.w * inv + bv.w;
        o.x = (o.x > 0.f) ? o.x : expm1f(o.x);   // ELU
        o.y = (o.y > 0.f) ? o.y : expm1f(o.y);
        o.z = (o.z > 0.f) ? o.z : expm1f(o.z);
        o.w = (o.w > 0.f) ? o.w : expm1f(o.w);
        u16 hx = bf16rn(o.x), hy = bf16rn(o.y), hz = bf16rn(o.z), hw = bf16rn(o.w);
        ushort4 H = make_ushort4(hx, hy, hz, hw);
        ushort4 L = make_ushort4(bf16rn(o.x - bf16f(hx)), bf16rn(o.y - bf16f(hy)),
                                 bf16rn(o.z - bf16f(hz)), bf16rn(o.w - bf16f(hw)));
        *reinterpret_cast<ushort4*>(&ghi[(size_t)d * 256 + c0]) = H;
        *reinterpret_cast<ushort4*>(&glo[(size_t)d * 256 + c0]) = L;
    }
}

// ---------------- layer-3 aggregate (1 head) fused with node attn gate ------
__global__ __launch_bounds__(256) void gat_aggregate1_attn_k(
        const float* __restrict__ hin, const float* __restrict__ esrc,
        const float* __restrict__ edst, const int* __restrict__ rowptr,
        const int* __restrict__ srcs, const float* __restrict__ bias,
        const float* __restrict__ wp, const float* __restrict__ bp,
        float* __restrict__ gout, float* __restrict__ attn, int n) {
    __shared__ int2 swb[4][64];
    int wv = threadIdx.x >> 6;
    int d = blockIdx.x * 4 + wv;
    int lane = threadIdx.x & 63;
    if (d >= n) return;
    const int es = lane >> 4;
    const int cq = lane & 15;
    int2* swv = swb[wv];
    float ed = edst[d];
    int lo = rowptr[d], hi = rowptr[d + 1];
    float den = 0.f;
    float4 acc = make_float4(0.f, 0.f, 0.f, 0.f);
    for (int base = lo; base < hi; base += 64) {
        int cnt = min(64, hi - base);
        int idx = base + lane;
        int s = srcs[(idx < hi) ? idx : lo];
        swv[lane].x = s;
        auto ROWL = [&](int j) -> float4 {
            int sp = swv[j].x;
            return *reinterpret_cast<const float4*>(&hin[(size_t)sp * 64 + cq * 4]);
        };
        float4 z = make_float4(0.f, 0.f, 0.f, 0.f);
        float4 r0 = z, r1 = z, r2 = z, r3 = z, r4 = z, r5 = z, r6 = z, r7 = z;
        r0 = ROWL(es);
        if (cnt > 4)  r1 = ROWL(4 + es);
        if (cnt > 8)  r2 = ROWL(8 + es);
        if (cnt > 12) r3 = ROWL(12 + es);
        if (cnt > 16) r4 = ROWL(16 + es);
        if (cnt > 20) r5 = ROWL(20 + es);
        if (cnt > 24) r6 = ROWL(24 + es);
        if (cnt > 28) r7 = ROWL(28 + es);
        float e = esrc[s] + ed;
        e = (e >= 0.f) ? e : 0.2f * e;
        float w = (lane < cnt) ? __expf(e) : 0.f;
        float ws = w;
#pragma unroll
        for (int off = 1; off < 64; off <<= 1) ws += __shfl_xor(ws, off);
        den += ws;
        swv[lane].y = __float_as_int(w);
        AGG_STEP(0, r0) AGG_STEP(1, r1) AGG_STEP(2, r2) AGG_STEP(3, r3)
        AGG_STEP(4, r4) AGG_STEP(5, r5) AGG_STEP(6, r6) AGG_STEP(7, r7)
        if (cnt > 32) {
            r0 = ROWL(32 + es);
            if (cnt > 36) r1 = ROWL(36 + es);
            if (cnt > 40) r2 = ROWL(40 + es);
            if (cnt > 44) r3 = ROWL(44 + es);
            if (cnt > 48) r4 = ROWL(48 + es);
            if (cnt > 52) r5 = ROWL(52 + es);
            if (cnt > 56) r6 = ROWL(56 + es);
            if (cnt > 60) r7 = ROWL(60 + es);
            AGG_STEP(8, r0)  AGG_STEP(9, r1)  AGG_STEP(10, r2) AGG_STEP(11, r3)
            AGG_STEP(12, r4) AGG_STEP(13, r5) AGG_STEP(14, r6) AGG_STEP(15, r7)
        }
    }
    acc.x += __shfl_xor(acc.x, 16); acc.x += __shfl_xor(acc.x, 32);
    acc.y += __shfl_xor(acc.y, 16); acc.y += __shfl_xor(acc.y, 32);
    acc.z += __shfl_xor(acc.z, 16); acc.z += __shfl_xor(acc.z, 32);
    acc.w += __shfl_xor(acc.w, 16); acc.w += __shfl_xor(acc.w, 32);
    int c0 = cq * 4;
    float inv = 1.f / den;
    float4 bv = *reinterpret_cast<const float4*>(&bias[c0]);
    float4 o;
    o.x = acc.x * inv + bv.x;
    o.y = acc.y * inv + bv.y;
    o.z = acc.z * inv + bv.z;
    o.w = acc.w * inv + bv.w;
    o.x = (o.x > 0.f) ? o.x : expm1f(o.x);       // ELU
    o.y = (o.y > 0.f) ? o.y : expm1f(o.y);
    o.z = (o.z > 0.f) ? o.z : expm1f(o.z);
    o.w = (o.w > 0.f) ? o.w : expm1f(o.w);
    if (es == 0)
        *reinterpret_cast<float4*>(&gout[(size_t)d * 64 + c0]) = o;
    // node attention gate: full 64-ch dot (cq lanes each hold 4 channels)
    float4 wv4 = *reinterpret_cast<const float4*>(&wp[c0]);
    float v = o.x * wv4.x + o.y * wv4.y + o.z * wv4.z + o.w * wv4.w;
#pragma unroll
    for (int off = 1; off < 16; off <<= 1) v += __shfl_xor(v, off);
    if (lane == 0) attn[d] = 1.f / (1.f + __expf(-(v + bp[0])));
}

// ---------------- parallel segmented pooling (batch is sorted) --------------
__global__ void pool_partial_k(const float* __restrict__ g3, const float* __restrict__ attn,
                               const int* __restrict__ batch, int n, float* __restrict__ sums) {
    int wid = blockIdx.x * (blockDim.x >> 6) + (threadIdx.x >> 6);
    int lane = threadIdx.x & 63;
    int nwaves = gridDim.x * (blockDim.x >> 6);
    int per = (n + nwaves - 1) / nwaves;
    int i0 = wid * per;
    int i1 = i0 + per;
    if (i1 > n) i1 = n;
    if (i0 >= i1) return;
    int cur = batch[i0];
    float acc = 0.f;
    for (int i = i0; i < i1; ++i) {
        int b = batch[i];
        if (b != cur) {
            atomicAdd(&sums[cur * 64 + lane], acc);
            acc = 0.f;
            cur = b;
        }
        acc += g3[(size_t)i * 64 + lane] * attn[i];
    }
    atomicAdd(&sums[cur * 64 + lane], acc);
}

// ---------------- final regressor: one block, wave per graph ----------------
__global__ void regress_k(const float* __restrict__ sums, const int* __restrict__ batch, int n,
                          const float* __restrict__ wr, const float* __restrict__ br,
                          float* __restrict__ out, int B) {
    int b = threadIdx.x >> 6;
    int lane = threadIdx.x & 63;
    if (b >= B) return;
    int lo = 0, hi = n;
    while (lo < hi) { int mid = (lo + hi) >> 1; if (batch[mid] < b) lo = mid + 1; else hi = mid; }
    int seg_lo = lo;
    lo = 0; hi = n;
    while (lo < hi) { int mid = (lo + hi) >> 1; if (batch[mid] < b + 1) lo = mid + 1; else hi = mid; }
    float cnt = (float)(lo - seg_lo);
    if (cnt < 1.f) cnt = 1.f;
    float v = (sums[b * 64 + lane] / cnt) * wr[lane];
#pragma unroll
    for (int off = 32; off; off >>= 1) v += __shfl_xor(v, off);
    if (lane == 0) out[b] = v + br[0];
}

// ---------------------------------------------------------------------------
extern "C" void kernel_launch(void* const* d_in, const int* in_sizes, int n_in,
                              void* d_out, int out_size, void* d_ws, size_t ws_size,
                              hipStream_t stream) {
    const float* x   = (const float*)d_in[0];
    const int*   ei  = (const int*)d_in[1];
    const int*   bat = (const int*)d_in[2];
    const float* W1  = (const float*)d_in[3];
    const float* as1 = (const float*)d_in[4];
    const float* ad1 = (const float*)d_in[5];
    const float* b1  = (const float*)d_in[6];
    const float* W2  = (const float*)d_in[7];
    const float* as2 = (const float*)d_in[8];
    const float* ad2 = (const float*)d_in[9];
    const float* b2  = (const float*)d_in[10];
    const float* W3  = (const float*)d_in[11];
    const float* as3 = (const float*)d_in[12];
    const float* ad3 = (const float*)d_in[13];
    const float* b3  = (const float*)d_in[14];
    const float* wp  = (const float*)d_in[15];
    const float* bp  = (const float*)d_in[16];
    const float* wr  = (const float*)d_in[17];
    const float* br  = (const float*)d_in[18];
    float* out = (float*)d_out;

    const int N    = in_sizes[2];          // 20000
    const int E    = in_sizes[1] / 2;      // 320000
    const int DIN  = in_sizes[0] / N;      // 128
    const int Etot = E + N;
    const int Bc   = out_size;             // 16

    char* ws = (char*)d_ws;
    size_t off = 0;
    auto alloc = [&](size_t bytes) {
        void* p = ws + off;
        off = (off + bytes + 255) & ~(size_t)255;
        return p;
    };
    int*   deg    = (int*)alloc((size_t)N * 4);
    int*   rowptr = (int*)alloc((size_t)(N + 1) * 4);
    int*   cursor = (int*)alloc((size_t)N * 4);
    int*   bsum   = (int*)alloc((size_t)1024 * 4);
    int*   srcs   = (int*)alloc((size_t)Etot * 4);
    float* bufA   = (float*)alloc((size_t)N * 256 * 4);     // GEMM out h (head-major)
    u16*   Ahi    = (u16*)alloc((size_t)N * 256 * 2);       // x/g split hi
    u16*   Alo    = (u16*)alloc((size_t)N * 256 * 2);       // x/g split lo
    float* h3     = (float*)alloc((size_t)N * 64 * 4);
    float* g3     = (float*)alloc((size_t)N * 64 * 4);
    float* esrc   = (float*)alloc((size_t)N * 4 * 4);
    float* edst   = (float*)alloc((size_t)N * 4 * 4);
    float* attn   = (float*)alloc((size_t)N * 4);
    float* sums   = (float*)alloc((size_t)Bc * 64 * 4);
    u16*   w1hi   = (u16*)alloc((size_t)256 * DIN * 2);
    u16*   w1lo   = (u16*)alloc((size_t)256 * DIN * 2);
    u16*   w2hi   = (u16*)alloc((size_t)256 * 256 * 2);
    u16*   w2lo   = (u16*)alloc((size_t)256 * 256 * 2);
    u16*   w3hi   = (u16*)alloc((size_t)64 * 256 * 2);
    u16*   w3lo   = (u16*)alloc((size_t)64 * 256 * 2);
    (void)ws_size;

    // CSR build (shared by all layers); hierarchical parallel scan
    hipMemsetAsync(deg, 0, (size_t)N * 4, stream);
    int eb = (Etot + 255) / 256;
    int nb = (N + 255) / 256;              // 79 blocks <= 1024
    edge_hist_k<<<eb, 256, 0, stream>>>(ei, E, N, deg);
    scan_p1_k<<<nb, 256, 0, stream>>>(deg, bsum, N);
    scan_p2_k<<<1, 1024, 0, stream>>>(bsum, nb);
    scan_p3_k<<<nb, 256, 0, stream>>>(deg, bsum, rowptr, cursor, N);
    edge_scatter_k<<<eb, 256, 0, stream>>>(ei, E, N, cursor, srcs);

    // weight splits (transposed) + x split
    splitT_bf16_k<<<(DIN * 256 + 255) / 256, 256, 0, stream>>>(W1, w1hi, w1lo, DIN, 256);
    splitT_bf16_k<<<(256 * 256 + 255) / 256, 256, 0, stream>>>(W2, w2hi, w2lo, 256, 256);
    splitT_bf16_k<<<(256 * 64 + 255) / 256, 256, 0, stream>>>(W3, w3hi, w3lo, 256, 64);
    split_bf16_k<<<(N * DIN / 4 + 255) / 256, 256, 0, stream>>>(x, Ahi, Alo, N * DIN / 4);

    const int mb = (N + 63) / 64;          // 313
    int nb4 = (N + 3) / 4;
    dim3 agg_grid(nb4, 4);

    // Layer 1: DIN -> (4,64) concat      (BN=128 -> 2 n-tiles)
    gemm_lds_k<2><<<mb * 2, 256, 0, stream>>>(Ahi, Alo, w1hi, w1lo, bufA, as1, ad1, esrc, edst, N, 256, DIN);
    gat_aggregate_hm_k<<<agg_grid, 256, 0, stream>>>(bufA, esrc, edst, rowptr, srcs, b1, Ahi, Alo, N);

    // Layer 2: 256 -> (4,64) concat
    gemm_lds_k<2><<<mb * 2, 256, 0, stream>>>(Ahi, Alo, w2hi, w2lo, bufA, as2, ad2, esrc, edst, N, 256, 256);
    gat_aggregate_hm_k<<<agg_grid, 256, 0, stream>>>(bufA, esrc, edst, rowptr, srcs, b2, Ahi, Alo, N);

    // Layer 3: 256 -> (1,64) mean + fused node-attention gate   (BN=64)
    gemm_lds_k<1><<<mb, 256, 0, stream>>>(Ahi, Alo, w3hi, w3lo, h3, as3, ad3, esrc, edst, N, 64, 256);
    gat_aggregate1_attn_k<<<nb4, 256, 0, stream>>>(h3, esrc, edst, rowptr, srcs, b3, wp, bp, g3, attn, N);

    // Attention pool + regressor (parallel)
    hipMemsetAsync(sums, 0, (size_t)Bc * 64 * 4, stream);
    pool_partial_k<<<256, 256, 0, stream>>>(g3, attn, bat, N, sums);
    regress_k<<<1, 1024, 0, stream>>>(sums, bat, N, wr, br, out, Bc);
}